// Round 5
// baseline (6085.178 us; speedup 1.0000x reference)
//
#include <hip/hip_runtime.h>
#include <hip/hip_bf16.h>
#include <cfloat>

using bf16 = __hip_bfloat16;

constexpr int Bb = 8, Nn = 4096, Kk = 20;
constexpr int BN = Bb * Nn;                     // 32768
constexpr int Mrows = BN * Kk;                  // 655360
constexpr float EPSf = 1e-5f;

static __device__ __forceinline__ float b2f(bf16 v){ return __bfloat162float(v); }
static __device__ __forceinline__ bf16 f2b(float v){ return __float2bfloat16(v); }
static __device__ __forceinline__ unsigned short f2bu(float v){
  union { bf16 b; unsigned short u; } cv; cv.b = __float2bfloat16(v); return cv.u;
}
static __device__ __forceinline__ float ldf(bf16 v){ return b2f(v); }
static __device__ __forceinline__ float ldf(float v){ return v; }
// float4-granule XOR swizzle: kills 4-way bank aliasing for 32B-strided reads
static __device__ __forceinline__ int sw4(int g){ return g ^ (g >> 3); }

// ---------------- zero workspace region ----------------
__global__ void zero_kernel(float* __restrict__ p, int n){
  int i = blockIdx.x*256 + threadIdx.x;
  if (i < n) p[i] = 0.f;
}

// ---------------- KNN phase A: per-point top-20 over a j-stripe (4 stripes) ----------------
__global__ __launch_bounds__(256) void knnA_kernel(const float* __restrict__ x,
                                                   float* __restrict__ pv, int* __restrict__ pi){
#pragma clang fp contract(off)
  __shared__ float4 p4[1024];
  int blk = blockIdx.x;
  int stripe = blk & 3;
  int chunk  = (blk >> 2) & 15;
  int b      = blk >> 6;
  const float* xb = x + b*3*Nn;
  int j0 = stripe*1024;
  for (int u = threadIdx.x; u < 1024; u += 256){
    int j = j0 + u;
    float a0 = xb[j];
    float a1 = xb[Nn + j];
    float a2 = xb[2*Nn + j];
    float s = a0*a0; s = s + a1*a1; s = s + a2*a2;   // xx = ((x^2)+(y^2))+(z^2)
    p4[u] = make_float4(a0, a1, a2, s);
  }
  __syncthreads();
  int i = chunk*256 + threadIdx.x;
  float xi = xb[i], yi = xb[Nn+i], zi = xb[2*Nn+i];
  float ni = xi*xi; ni = ni + yi*yi; ni = ni + zi*zi;
  float mni = -ni;
  float tv[Kk]; int ti[Kk];
  #pragma unroll
  for (int s=0;s<Kk;++s){ tv[s] = -FLT_MAX; ti[s] = 0; }
  for (int u=0; u<1024; ++u){
    float4 p = p4[u];
    float dot = xi*p.x; dot = dot + yi*p.y; dot = dot + zi*p.z;
    float inner = -2.0f*dot;
    float nd = mni - inner; nd = nd - p.w;            // (-xx_i - inner) - xx_j
    if (nd > tv[Kk-1]){
      #pragma unroll
      for (int s=Kk-1; s>=1; --s){
        bool cs = nd > tv[s];
        bool cp = nd > tv[s-1];
        tv[s] = cs ? (cp ? tv[s-1] : nd) : tv[s];
        ti[s] = cs ? (cp ? ti[s-1] : (j0+u)) : ti[s];
      }
      if (nd > tv[0]){ tv[0] = nd; ti[0] = j0+u; }
    }
  }
  long long base = ((long long)(b*Nn + i)*4 + stripe)*Kk;
  #pragma unroll
  for (int s=0;s<Kk;++s){ pv[base+s] = tv[s]; pi[base+s] = ti[s]; }
}

// ---------------- KNN phase B: merge the four stripe lists ----------------
__global__ __launch_bounds__(256) void knnB_kernel(const float* __restrict__ pv,
                                                   const int* __restrict__ pi,
                                                   int* __restrict__ idx){
  int p = blockIdx.x*256 + threadIdx.x;
  if (p >= BN) return;
  long long base = (long long)p*4*Kk;
  float av[Kk]; int ai[Kk];
  #pragma unroll
  for (int s=0;s<Kk;++s){ av[s]=pv[base+s]; ai[s]=pi[base+s]; }
  for (int t=Kk; t<4*Kk; ++t){
    float nd = pv[base+t]; int j = pi[base+t];
    if (nd > av[Kk-1]){
      #pragma unroll
      for (int s=Kk-1;s>=1;--s){
        bool cs = nd > av[s];
        bool cp = nd > av[s-1];
        av[s] = cs ? (cp?av[s-1]:nd) : av[s];
        ai[s] = cs ? (cp?ai[s-1]:j) : ai[s];
      }
      if (nd > av[0]){ av[0]=nd; ai[0]=j; }
    }
  }
  #pragma unroll
  for (int s=0;s<Kk;++s) idx[(long long)p*Kk+s] = ai[s];
}

// ---------------- layer-1 feature stats: sum(f) and f^T f (6x6) ----------------
__global__ __launch_bounds__(256) void gramf_kernel(const float* __restrict__ x,
                                                    const int* __restrict__ idx,
                                                    float* __restrict__ part){
  float acc[36]; float s6[6];
  #pragma unroll
  for (int a=0;a<36;++a) acc[a]=0.f;
  #pragma unroll
  for (int a=0;a<6;++a) s6[a]=0.f;
  for (long long row = blockIdx.x*256 + threadIdx.x; row < Mrows; row += (long long)gridDim.x*256){
    int bn = (int)(row / Kk);
    int b = bn >> 12, n = bn & 4095;
    int j = idx[row];
    const float* xb = x + b*3*Nn;
    float f[6];
    f[0]=xb[j];  f[1]=xb[Nn+j];  f[2]=xb[2*Nn+j];
    f[3]=xb[n];  f[4]=xb[Nn+n];  f[5]=xb[2*Nn+n];
    #pragma unroll
    for (int a=0;a<6;++a){
      s6[a] += f[a];
      #pragma unroll
      for (int c=0;c<6;++c) acc[a*6+c] = fmaf(f[a], f[c], acc[a*6+c]);
    }
  }
  __shared__ float red[256];
  for (int v=0; v<42; ++v){
    red[threadIdx.x] = (v<36)? acc[v] : s6[v-36];
    __syncthreads();
    for (int s=128; s>0; s>>=1){
      if (threadIdx.x < s) red[threadIdx.x] += red[threadIdx.x+s];
      __syncthreads();
    }
    if (threadIdx.x==0) part[blockIdx.x*48 + v] = red[0];
    __syncthreads();
  }
}

__global__ void reducef_kernel(const float* __restrict__ part, float* __restrict__ Gf,
                               float* __restrict__ sumf){
  int t = threadIdx.x;
  if (t < 42){
    float s = 0.f;
    for (int i=0;i<256;++i) s += part[i*48 + t];
    if (t<36) Gf[t]=s; else sumf[t-36]=s;
  }
}

// ---------------- Gram: G = H^T H, 64x64 tiles ----------------
template<int CIN, typename T>
__global__ __launch_bounds__(256) void gram_kernel(const T* __restrict__ H, int M,
                                                   float* __restrict__ G){
  constexpr int Tt = CIN/64;
  int tile = blockIdx.x % (Tt*Tt);
  int chunk = blockIdx.x / (Tt*Tt);
  int nchunks = gridDim.x / (Tt*Tt);
  int tr = tile / Tt, tc = tile % Tt;
  __shared__ float Aw[16][64];
  __shared__ float Bw[16][64];
  int rpc = (M + nchunks - 1)/nchunks;
  int r0 = chunk*rpc; int r1 = min(M, r0+rpc);
  int tx = threadIdx.x & 15, ty = threadIdx.x >> 4;
  float acc[4][4] = {};
  for (int rb=r0; rb<r1; rb+=16){
    int nr = min(16, r1-rb);
    for (int u=threadIdx.x; u<1024; u+=256){
      int rr = u >> 6, cc = u & 63;
      float av=0.f, bv=0.f;
      if (rr < nr){
        const T* hp = H + (size_t)(rb+rr)*CIN;
        av = ldf(hp[tr*64+cc]);
        bv = ldf(hp[tc*64+cc]);
      }
      Aw[rr][cc]=av; Bw[rr][cc]=bv;
    }
    __syncthreads();
    for (int r=0;r<nr;++r){
      float4 af = *(const float4*)&Aw[r][ty*4];
      float4 bf = *(const float4*)&Bw[r][tx*4];
      float a[4] = {af.x, af.y, af.z, af.w};
      float bq[4] = {bf.x, bf.y, bf.z, bf.w};
      #pragma unroll
      for (int u=0;u<4;++u)
        #pragma unroll
        for (int v=0;v<4;++v) acc[u][v] = fmaf(a[u], bq[v], acc[u][v]);
    }
    __syncthreads();
  }
  #pragma unroll
  for (int u=0;u<4;++u)
    #pragma unroll
    for (int v=0;v<4;++v)
      atomicAdd(&G[(size_t)(tr*64+ty*4+u)*CIN + (tc*64+tx*4+v)], acc[u][v]);
}

// ---------------- column sums of H ----------------
template<int CIN, typename T>
__global__ __launch_bounds__(256) void colsum_kernel(const T* __restrict__ H, int M,
                                                     float* __restrict__ sumh){
  int rpb = (M + gridDim.x - 1)/gridDim.x;
  int r0 = blockIdx.x*rpb, r1 = min(M, r0+rpb);
  if constexpr (CIN <= 256){
    constexpr int RP = 256/CIN;
    int c = threadIdx.x % CIN;
    int sub = threadIdx.x / CIN;
    float a = 0.f;
    for (int r=r0+sub; r<r1; r+=RP) a += ldf(H[(size_t)r*CIN + c]);
    atomicAdd(&sumh[c], a);
  } else {
    float a0=0.f, a1=0.f;
    for (int r=r0;r<r1;++r){
      a0 += ldf(H[(size_t)r*CIN + threadIdx.x]);
      a1 += ldf(H[(size_t)r*CIN + threadIdx.x + 256]);
    }
    atomicAdd(&sumh[threadIdx.x], a0);
    atomicAdd(&sumh[threadIdx.x+256], a1);
  }
}

// ---------------- P = G @ W ----------------
__global__ void kP_kernel(const float* __restrict__ G, const float* __restrict__ Wf,
                          float* __restrict__ P, int Cin, int Cout){
  int id = blockIdx.x*256 + threadIdx.x;
  if (id >= Cin*Cout) return;
  int i = id / Cout, j = id - i*Cout;
  float s = 0.f;
  for (int k=0;k<Cin;++k) s = fmaf(G[(size_t)i*Cin+k], Wf[(size_t)k*Cout+j], s);
  P[id] = s;
}

// ---------------- scale/shift from Gram-derived BN stats ----------------
__global__ void kFinal_kernel(const float* __restrict__ P, const float* __restrict__ sumh,
                              const float* __restrict__ Wf, const float* __restrict__ g,
                              const float* __restrict__ bb, float* __restrict__ scale,
                              float* __restrict__ shift, int Cin, int Cout, float invM){
  int j = blockIdx.x*256 + threadIdx.x;
  if (j >= Cout) return;
  float mean=0.f, e2=0.f;
  for (int i=0;i<Cin;++i){
    float w = Wf[(size_t)i*Cout + j];
    mean = fmaf(sumh[i], w, mean);
    e2   = fmaf(w, P[(size_t)i*Cout + j], e2);
  }
  mean *= invM; e2 *= invM;
  float var = e2 - mean*mean;
  float inv = rsqrtf(var + EPSf);
  float sc = g[j]*inv;
  scale[j]=sc;
  shift[j]=bb[j] - mean*sc;
}

// ---------------- layer-2 stats: on-the-fly H1 -> Gram2(64x64) + colsum2 ----------------
__global__ __launch_bounds__(256) void stats2_kernel(const float* __restrict__ x,
    const int* __restrict__ idx, const float* __restrict__ W1f,
    const float* __restrict__ sc1v, const float* __restrict__ sh1v,
    float* __restrict__ G2, float* __restrict__ sum2){
  __shared__ float W1s[6][64];
  __shared__ float fsh[16][6];
  __shared__ float Aw[16][64];
  __shared__ float scs[64], shs[64];
  int tid = threadIdx.x;
  for (int u=tid; u<384; u+=256) W1s[u/64][u%64] = W1f[u];
  if (tid < 64){ scs[tid]=sc1v[tid]; shs[tid]=sh1v[tid]; }
  __syncthreads();
  int rpc = (Mrows + gridDim.x - 1)/gridDim.x;
  int r0 = blockIdx.x*rpc, r1 = min(Mrows, r0+rpc);
  int ty = tid >> 4, tx = tid & 15;
  int myc = tid & 63;
  float acc[4][4] = {};
  float cs = 0.f;
  for (int rb=r0; rb<r1; rb+=16){
    if (tid < 16){
      int row = rb + tid;
      float f0=0,f1=0,f2=0,f3=0,f4=0,f5=0;
      if (row < r1){
        int bn = row / Kk;
        int b = bn >> 12, n = bn & 4095;
        int j = idx[row];
        const float* xb = x + b*3*Nn;
        f0=xb[j]; f1=xb[Nn+j]; f2=xb[2*Nn+j];
        f3=xb[n]; f4=xb[Nn+n]; f5=xb[2*Nn+n];
      }
      fsh[tid][0]=f0; fsh[tid][1]=f1; fsh[tid][2]=f2;
      fsh[tid][3]=f3; fsh[tid][4]=f4; fsh[tid][5]=f5;
    }
    __syncthreads();
    #pragma unroll
    for (int k=0;k<4;++k){
      int rr = (tid>>6) + k*4;
      float y = 0.f;
      #pragma unroll
      for (int i=0;i<6;++i) y = fmaf(fsh[rr][i], W1s[i][myc], y);
      float v = fmaxf(fmaf(y, scs[myc], shs[myc]), 0.f);
      if (rb + rr >= r1) v = 0.f;
      Aw[rr][myc] = v;
      cs += v;
    }
    __syncthreads();
    for (int r=0;r<16;++r){
      float4 af = *(const float4*)&Aw[r][ty*4];
      float4 bf = *(const float4*)&Aw[r][tx*4];
      float a[4] = {af.x, af.y, af.z, af.w};
      float bq[4] = {bf.x, bf.y, bf.z, bf.w};
      #pragma unroll
      for (int u=0;u<4;++u)
        #pragma unroll
        for (int v=0;v<4;++v) acc[u][v]=fmaf(a[u],bq[v],acc[u][v]);
    }
    __syncthreads();
  }
  #pragma unroll
  for (int u=0;u<4;++u)
    #pragma unroll
    for (int v=0;v<4;++v)
      atomicAdd(&G2[(size_t)(ty*4+u)*64 + tx*4+v], acc[u][v]);
  atomicAdd(&sum2[myc], cs);
}

// ---------------- fused layers 1+2: gather->H1->x1, H1@W2 -> H2(bf16) + x2 ----------------
__global__ __launch_bounds__(64) void fl12_kernel(const float* __restrict__ x,
    const int* __restrict__ idx, const float* __restrict__ W1f,
    const float* __restrict__ sc1v, const float* __restrict__ sh1v,
    const float* __restrict__ W2f, const float* __restrict__ sc2v,
    const float* __restrict__ sh2v, bf16* __restrict__ H2, bf16* __restrict__ cat){
  __shared__ float fsh[Kk][6];
  __shared__ float h1[Kk][64];
  __shared__ float mm[4][64];
  int bn = blockIdx.x, b = bn>>12, n = bn & 4095;
  int tid = threadIdx.x;
  if (tid < Kk){
    int j = idx[(size_t)bn*Kk + tid];
    const float* xb = x + b*3*Nn;
    fsh[tid][0]=xb[j]; fsh[tid][1]=xb[Nn+j]; fsh[tid][2]=xb[2*Nn+j];
    fsh[tid][3]=xb[n]; fsh[tid][4]=xb[Nn+n]; fsh[tid][5]=xb[2*Nn+n];
  }
  __syncthreads();
  {
    float sc=sc1v[tid], sh=sh1v[tid];
    float w[6];
    #pragma unroll
    for (int i=0;i<6;++i) w[i]=W1f[i*64+tid];
    float mx = 0.f;
    #pragma unroll
    for (int r=0;r<Kk;++r){
      float y=0.f;
      #pragma unroll
      for (int i=0;i<6;++i) y = fmaf(fsh[r][i], w[i], y);
      float v = fmaxf(fmaf(y,sc,sh),0.f);
      h1[r][tid]=v;
      mx = fmaxf(mx,v);
    }
    cat[(size_t)bn*512 + tid] = f2b(mx);
  }
  __syncthreads();
  int q = tid >> 4, c0 = (tid & 15)*4;
  float acc[5][4]={};
  for (int i0=0;i0<64;i0+=4){
    float hv[5][4];
    #pragma unroll
    for (int l=0;l<5;++l){
      float4 t4 = *(const float4*)&h1[q*5+l][i0];
      hv[l][0]=t4.x; hv[l][1]=t4.y; hv[l][2]=t4.z; hv[l][3]=t4.w;
    }
    #pragma unroll
    for (int ii=0;ii<4;++ii){
      const float* wp = W2f + (i0+ii)*64 + c0;
      float w0=wp[0],w1=wp[1],w2=wp[2],w3=wp[3];
      #pragma unroll
      for (int l=0;l<5;++l){
        float hvv=hv[l][ii];
        acc[l][0]=fmaf(hvv,w0,acc[l][0]);
        acc[l][1]=fmaf(hvv,w1,acc[l][1]);
        acc[l][2]=fmaf(hvv,w2,acc[l][2]);
        acc[l][3]=fmaf(hvv,w3,acc[l][3]);
      }
    }
  }
  float sc[4],sh[4];
  #pragma unroll
  for (int cb=0;cb<4;++cb){ sc[cb]=sc2v[c0+cb]; sh[cb]=sh2v[c0+cb]; }
  float mx[4]={0,0,0,0};
  #pragma unroll
  for (int l=0;l<5;++l){
    unsigned short us[4];
    #pragma unroll
    for (int cb=0;cb<4;++cb){
      float v=fmaxf(fmaf(acc[l][cb],sc[cb],sh[cb]),0.f);
      mx[cb]=fmaxf(mx[cb],v);
      us[cb]=f2bu(v);
    }
    uint2 v2; v2.x = us[0]|((unsigned)us[1]<<16); v2.y=us[2]|((unsigned)us[3]<<16);
    *(uint2*)(H2 + ((size_t)bn*Kk + q*5+l)*64 + c0) = v2;
  }
  #pragma unroll
  for (int cb=0;cb<4;++cb) mm[q][c0+cb]=mx[cb];
  __syncthreads();
  {
    float M0 = fmaxf(fmaxf(mm[0][tid],mm[1][tid]),fmaxf(mm[2][tid],mm[3][tid]));
    cat[(size_t)bn*512 + 64 + tid] = f2b(M0);
  }
}

// ---------------- layer-4 stats: on-the-fly H3 -> Gram4(128x128) + colsum4 ----------------
// __launch_bounds__(256,2): <=256 VGPR so the 64-reg Gram accumulator never spills.
__global__ __launch_bounds__(256,2) void stats4_kernel(const bf16* __restrict__ H2,
    const float* __restrict__ W3f, const float* __restrict__ sc3v, const float* __restrict__ sh3v,
    float* __restrict__ G4, float* __restrict__ sum4){
  __shared__ float W3s[64][128];
  __shared__ float h2s[16][64];
  __shared__ float h3s[16*128];   // float4-granule XOR-swizzled, stride 128 floats
  __shared__ float scs[128], shs[128];
  int tid = threadIdx.x;
  for (int u=tid; u<64*128; u+=256) W3s[u>>7][u&127]=W3f[u];
  if (tid<128){ scs[tid]=sc3v[tid]; shs[tid]=sh3v[tid]; }
  __syncthreads();
  int rpc=(Mrows+gridDim.x-1)/gridDim.x;
  int r0=blockIdx.x*rpc, r1=min(Mrows,r0+rpc);
  int ty=tid>>4, tx=tid&15;             // gram 8x8 tile
  int rr2=tid>>5, cg=tid&31;            // produce: rows {2*rr2,2*rr2+1}, granule cg
  int wrg = sw4(cg)*4;                  // swizzled write column
  int ga0 = sw4(2*ty)*4, ga1 = sw4(2*ty+1)*4;
  int gb0 = sw4(2*tx)*4, gb1 = sw4(2*tx+1)*4;
  float acc[8][8]={};
  float cs[4]={0.f,0.f,0.f,0.f};
  float sca[4], sha[4];
  #pragma unroll
  for (int k=0;k<4;++k){ sca[k]=sc3v[cg*4+k]; sha[k]=sh3v[cg*4+k]; }
  for (int rb=r0; rb<r1; rb+=16){
    for (int u=tid; u<1024; u+=256){
      int rr=u>>6, cc=u&63;
      float v=0.f;
      int row=rb+rr;
      if (row<r1) v=b2f(H2[(size_t)row*64+cc]);
      h2s[rr][cc]=v;
    }
    __syncthreads();
    // produce h3s: 2 rows x 4 cols per thread, i-ascending accumulation
    {
      float y0[4]={0,0,0,0}, y1[4]={0,0,0,0};
      int ra = rr2*2, rbb = rr2*2+1;
      for (int i=0;i<64;++i){
        float4 w = *(const float4*)&W3s[i][cg*4];
        float ha = h2s[ra][i], hb = h2s[rbb][i];
        y0[0]=fmaf(ha,w.x,y0[0]); y0[1]=fmaf(ha,w.y,y0[1]);
        y0[2]=fmaf(ha,w.z,y0[2]); y0[3]=fmaf(ha,w.w,y0[3]);
        y1[0]=fmaf(hb,w.x,y1[0]); y1[1]=fmaf(hb,w.y,y1[1]);
        y1[2]=fmaf(hb,w.z,y1[2]); y1[3]=fmaf(hb,w.w,y1[3]);
      }
      bool oka = (rb+ra < r1), okb = (rb+rbb < r1);
      float va[4], vb[4];
      #pragma unroll
      for (int k=0;k<4;++k){
        float v0 = fmaxf(fmaf(y0[k],sca[k],sha[k]),0.f);
        float v1 = fmaxf(fmaf(y1[k],sca[k],sha[k]),0.f);
        va[k] = oka ? v0 : 0.f;
        vb[k] = okb ? v1 : 0.f;
        cs[k] += va[k]; cs[k] += vb[k];
      }
      *(float4*)&h3s[ra*128  + wrg] = make_float4(va[0],va[1],va[2],va[3]);
      *(float4*)&h3s[rbb*128 + wrg] = make_float4(vb[0],vb[1],vb[2],vb[3]);
    }
    __syncthreads();
    for (int r=0;r<16;++r){
      const float* hr = &h3s[r*128];
      float4 a0 = *(const float4*)&hr[ga0];
      float4 a1 = *(const float4*)&hr[ga1];
      float4 b0 = *(const float4*)&hr[gb0];
      float4 b1 = *(const float4*)&hr[gb1];
      float a[8] = {a0.x,a0.y,a0.z,a0.w,a1.x,a1.y,a1.z,a1.w};
      float bq[8] = {b0.x,b0.y,b0.z,b0.w,b1.x,b1.y,b1.z,b1.w};
      #pragma unroll
      for (int u=0;u<8;++u)
        #pragma unroll
        for (int v=0;v<8;++v) acc[u][v]=fmaf(a[u],bq[v],acc[u][v]);
    }
    __syncthreads();
  }
  #pragma unroll
  for (int u=0;u<8;++u)
    #pragma unroll
    for (int v=0;v<8;++v)
      atomicAdd(&G4[(size_t)(ty*8+u)*128 + tx*8+v], acc[u][v]);
  #pragma unroll
  for (int k=0;k<4;++k) atomicAdd(&sum4[cg*4+k], cs[k]);
}

// ---------------- fused layers 3+4: 4 points/block. H2->H3->x3, H3@W4->x4 ----------------
__global__ __launch_bounds__(512,2) void fl34_kernel(const bf16* __restrict__ H2,
    const float* __restrict__ W3f, const float* __restrict__ sc3v, const float* __restrict__ sh3v,
    const float* __restrict__ W4f, const float* __restrict__ sc4v, const float* __restrict__ sh4v,
    bf16* __restrict__ cat){
  __shared__ float h2s[4][Kk][64];      // 20 KB
  __shared__ float h3s[4][Kk][128];     // 40 KB
  __shared__ float w4s[16][256];        // 16 KB, aliased as mm[4][4][256] after K-loop
  int tid = threadIdx.x;
  int bn0 = blockIdx.x*4;
  int pt = tid >> 7, tid2 = tid & 127;
  for (int u=tid; u<4*Kk*64; u+=512){
    int p = u / 1280, rem = u - p*1280;
    h2s[p][rem>>6][rem&63] = b2f(H2[((size_t)(bn0+p)*Kk + (rem>>6))*64 + (rem&63)]);
  }
  __syncthreads();
  // stage 1: H3 column tid2 for point pt, all 20 rows (i-ascending)
  {
    int c = tid2;
    float y[Kk];
    #pragma unroll
    for (int r=0;r<Kk;++r) y[r]=0.f;
    for (int i=0;i<64;++i){
      float w = W3f[i*128 + c];
      #pragma unroll
      for (int r=0;r<Kk;++r) y[r]=fmaf(h2s[pt][r][i], w, y[r]);
    }
    float sc=sc3v[c], sh=sh3v[c];
    float mx=0.f;
    #pragma unroll
    for (int r=0;r<Kk;++r){
      float v=fmaxf(fmaf(y[r],sc,sh),0.f);
      h3s[pt][r][c]=v;
      mx=fmaxf(mx,v);
    }
    cat[(size_t)(bn0+pt)*512 + 128 + c] = f2b(mx);
  }
  __syncthreads();
  // stage 2: Y4 = H3 @ W4; per point: 4 rowgroups(5) x 32 colgroups(8 strided)
  int q = tid2 >> 5, cbase = tid2 & 31;
  float acc[5][8]={};
  for (int i0=0;i0<128;i0+=16){
    for (int u=tid;u<4096;u+=512) w4s[u>>8][u&255]=W4f[(size_t)(i0+(u>>8))*256+(u&255)];
    __syncthreads();
    for (int ii=0;ii<16;++ii){
      float w[8];
      #pragma unroll
      for (int cb=0;cb<8;++cb) w[cb]=w4s[ii][cbase + cb*32];
      float hv[5];
      #pragma unroll
      for (int l=0;l<5;++l) hv[l]=h3s[pt][q*5+l][i0+ii];
      #pragma unroll
      for (int l=0;l<5;++l)
        #pragma unroll
        for (int cb=0;cb<8;++cb) acc[l][cb]=fmaf(hv[l],w[cb],acc[l][cb]);
    }
    __syncthreads();
  }
  float sc[8],sh[8];
  #pragma unroll
  for (int cb=0;cb<8;++cb){ sc[cb]=sc4v[cbase+cb*32]; sh[cb]=sh4v[cbase+cb*32]; }
  float mx[8];
  #pragma unroll
  for (int cb=0;cb<8;++cb) mx[cb]=0.f;
  #pragma unroll
  for (int l=0;l<5;++l)
    #pragma unroll
    for (int cb=0;cb<8;++cb){
      float v=fmaxf(fmaf(acc[l][cb],sc[cb],sh[cb]),0.f);
      mx[cb]=fmaxf(mx[cb],v);
    }
  float* mmf = &w4s[0][0];   // [4][4][256] alias (w4s dead after last sync)
  #pragma unroll
  for (int cb=0;cb<8;++cb) mmf[((pt*4+q)<<8) + cbase + cb*32] = mx[cb];
  __syncthreads();
  for (int u=tid; u<1024; u+=512){
    int p = u >> 8, c = u & 255;
    float M0 = fmaxf(fmaxf(mmf[((p*4+0)<<8)+c], mmf[((p*4+1)<<8)+c]),
                     fmaxf(mmf[((p*4+2)<<8)+c], mmf[((p*4+3)<<8)+c]));
    cat[(size_t)(bn0+p)*512 + 256 + c] = f2b(M0);
  }
}

// ---------------- layer 5: cat(bf16,512) @ W5, BN+ReLU, fp32 transposed store ----------------
__global__ __launch_bounds__(256) void l5_kernel(const bf16* __restrict__ cat,
                                                const float* __restrict__ Wf,
                                                const float* __restrict__ scale,
                                                const float* __restrict__ shift,
                                                float* __restrict__ out){
  __shared__ float cr[8][512];
  __shared__ float ob[8][512];
  int tid = threadIdx.x;
  int bn0 = blockIdx.x*8;
  for (int u=tid; u<8*512; u+=256) cr[u>>9][u&511] = b2f(cat[(size_t)bn0*512 + u]);
  __syncthreads();
  int rp = tid >> 6, cg = tid & 63, c0 = cg*8;
  int ra = rp*2, rb = rp*2+1;
  float acc[2][8] = {};
  for (int i=0;i<512;++i){
    float h0 = cr[ra][i], h1 = cr[rb][i];
    const float* wp = Wf + (size_t)i*512 + c0;
    float4 wa = *(const float4*)wp;
    float4 wb = *(const float4*)(wp+4);
    float w[8] = {wa.x,wa.y,wa.z,wa.w,wb.x,wb.y,wb.z,wb.w};
    #pragma unroll
    for (int k=0;k<8;++k){
      acc[0][k] = fmaf(h0, w[k], acc[0][k]);
      acc[1][k] = fmaf(h1, w[k], acc[1][k]);
    }
  }
  float sc[8], sh[8];
  #pragma unroll
  for (int k=0;k<8;++k){ sc[k]=scale[c0+k]; sh[k]=shift[c0+k]; }
  #pragma unroll
  for (int k=0;k<8;++k){
    ob[ra][c0+k] = fmaxf(fmaf(acc[0][k], sc[k], sh[k]), 0.f);
    ob[rb][c0+k] = fmaxf(fmaf(acc[1][k], sc[k], sh[k]), 0.f);
  }
  __syncthreads();
  int b = bn0 >> 12, n0 = bn0 & 4095;
  for (int u=tid; u<512; u+=256){
    float4 v0 = make_float4(ob[0][u], ob[1][u], ob[2][u], ob[3][u]);
    float4 v1 = make_float4(ob[4][u], ob[5][u], ob[6][u], ob[7][u]);
    float* op = out + ((size_t)b*512 + u)*4096 + n0;
    *(float4*)(op)   = v0;
    *(float4*)(op+4) = v1;
  }
}

extern "C" void kernel_launch(void* const* d_in, const int* in_sizes, int n_in,
                              void* d_out, int out_size, void* d_ws, size_t ws_size,
                              hipStream_t stream){
  const float* x   = (const float*)d_in[0];
  const float* W1f = (const float*)d_in[1];
  const float* W2f = (const float*)d_in[2];
  const float* W3f = (const float*)d_in[3];
  const float* W4f = (const float*)d_in[4];
  const float* W5f = (const float*)d_in[5];
  const float* g1=(const float*)d_in[6],  *b1=(const float*)d_in[7];
  const float* g2=(const float*)d_in[8],  *b2=(const float*)d_in[9];
  const float* g3=(const float*)d_in[10], *b3=(const float*)d_in[11];
  const float* g4=(const float*)d_in[12], *b4=(const float*)d_in[13];
  const float* g5=(const float*)d_in[14], *b5=(const float*)d_in[15];
  float* out = (float*)d_out;

  char* w = (char*)d_ws;
  size_t off = 0;
  auto alloc = [&](size_t bytes)->void*{
    void* p = w + off;
    off = (off + bytes + 255) & ~(size_t)255;
    return p;
  };

  int*  idxb = (int*) alloc((size_t)BN*Kk*4);          // 2.6 MB
  bf16* H2   = (bf16*)alloc((size_t)Mrows*64*2);       // 84 MB
  bf16* catb = (bf16*)alloc((size_t)BN*512*2);         // 33.6 MB
  // KNN scratch aliases H2 (H2 first written by fl12, after knnB is done)
  float* pv  = (float*)H2;                             // 10.5 MB
  int*   pib = (int*)((char*)H2 + (size_t)BN*4*Kk*4);  // 10.5 MB

  size_t statsStart = off;
  float* partf=(float*)alloc(256*48*4);
  float* Gf=(float*)alloc(36*4);
  float* sumf=(float*)alloc(8*4);
  float* G2=(float*)alloc(4096*4);   float* sum2=(float*)alloc(64*4);
  float* G3=(float*)alloc(4096*4);   float* sum3=(float*)alloc(64*4);
  float* G4=(float*)alloc(16384*4);  float* sum4=(float*)alloc(128*4);
  float* G5=(float*)alloc(262144*4); float* sum5=(float*)alloc(512*4);
  float* P1=(float*)alloc(384*4);
  float* P2=(float*)alloc(4096*4);
  float* P3=(float*)alloc(8192*4);
  float* P4=(float*)alloc(32768*4);
  float* P5=(float*)alloc(262144*4);
  float* sc1=(float*)alloc(64*4);   float* sh1=(float*)alloc(64*4);
  float* sc2=(float*)alloc(64*4);   float* sh2=(float*)alloc(64*4);
  float* sc3=(float*)alloc(128*4);  float* sh3=(float*)alloc(128*4);
  float* sc4=(float*)alloc(256*4);  float* sh4=(float*)alloc(256*4);
  float* sc5=(float*)alloc(512*4);  float* sh5=(float*)alloc(512*4);
  size_t statsEnd = off;

  int statsFloats = (int)((statsEnd - statsStart)/4);
  zero_kernel<<<(statsFloats+255)/256,256,0,stream>>>((float*)(w+statsStart), statsFloats);

  knnA_kernel<<<512,256,0,stream>>>(x, pv, pib);
  knnB_kernel<<<BN/256,256,0,stream>>>(pv, pib, idxb);

  const float invM  = 1.0f/(float)Mrows;
  const float invM5 = 1.0f/(float)BN;

  // layer 1 stats
  gramf_kernel<<<256,256,0,stream>>>(x, idxb, partf);
  reducef_kernel<<<1,64,0,stream>>>(partf, Gf, sumf);
  kP_kernel<<<2,256,0,stream>>>(Gf, W1f, P1, 6, 64);
  kFinal_kernel<<<1,256,0,stream>>>(P1, sumf, W1f, g1, b1, sc1, sh1, 6, 64, invM);

  // layer 2 stats (on-the-fly H1)
  stats2_kernel<<<2048,256,0,stream>>>(x, idxb, W1f, sc1, sh1, G2, sum2);
  kP_kernel<<<16,256,0,stream>>>(G2, W2f, P2, 64, 64);
  kFinal_kernel<<<1,256,0,stream>>>(P2, sum2, W2f, g2, b2, sc2, sh2, 64, 64, invM);

  // apply layers 1+2
  fl12_kernel<<<BN,64,0,stream>>>(x, idxb, W1f, sc1, sh1, W2f, sc2, sh2, H2, catb);

  // layer 3 stats from H2
  colsum_kernel<64,bf16><<<512,256,0,stream>>>(H2, Mrows, sum3);
  gram_kernel<64,bf16><<<2048,256,0,stream>>>(H2, Mrows, G3);
  kP_kernel<<<32,256,0,stream>>>(G3, W3f, P3, 64, 128);
  kFinal_kernel<<<1,256,0,stream>>>(P3, sum3, W3f, g3, b3, sc3, sh3, 64, 128, invM);

  // layer 4 stats (on-the-fly H3)
  stats4_kernel<<<2048,256,0,stream>>>(H2, W3f, sc3, sh3, G4, sum4);
  kP_kernel<<<128,256,0,stream>>>(G4, W4f, P4, 128, 256);
  kFinal_kernel<<<1,256,0,stream>>>(P4, sum4, W4f, g4, b4, sc4, sh4, 128, 256, invM);

  // apply layers 3+4 (4 points per block)
  fl34_kernel<<<BN/4,512,0,stream>>>(H2, W3f, sc3, sh3, W4f, sc4, sh4, catb);

  // layer 5
  colsum_kernel<512,bf16><<<512,256,0,stream>>>(catb, BN, sum5);
  gram_kernel<512,bf16><<<2048,256,0,stream>>>(catb, BN, G5);
  kP_kernel<<<1024,256,0,stream>>>(G5, W5f, P5, 512, 512);
  kFinal_kernel<<<2,256,0,stream>>>(P5, sum5, W5f, g5, b5, sc5, sh5, 512, 512, invM5);
  l5_kernel<<<BN/8,256,0,stream>>>(catb, W5f, sc5, sh5, out);
}

// Round 6
// 5078.189 us; speedup vs baseline: 1.1983x; 1.1983x over previous
//
#include <hip/hip_runtime.h>
#include <hip/hip_bf16.h>
#include <cfloat>

using bf16 = __hip_bfloat16;

constexpr int Bb = 8, Nn = 4096, Kk = 20;
constexpr int BN = Bb * Nn;                     // 32768
constexpr int Mrows = BN * Kk;                  // 655360
constexpr float EPSf = 1e-5f;

static __device__ __forceinline__ float b2f(bf16 v){ return __bfloat162float(v); }
static __device__ __forceinline__ bf16 f2b(float v){ return __float2bfloat16(v); }
static __device__ __forceinline__ unsigned short f2bu(float v){
  union { bf16 b; unsigned short u; } cv; cv.b = __float2bfloat16(v); return cv.u;
}
static __device__ __forceinline__ float ldf(bf16 v){ return b2f(v); }
static __device__ __forceinline__ float ldf(float v){ return v; }
// float4-granule XOR swizzle: 32 granules -> distinct bank-groups for strided reads
static __device__ __forceinline__ int sw4(int g){ return g ^ (g >> 3); }

// ---------------- zero workspace region ----------------
__global__ void zero_kernel(float* __restrict__ p, int n){
  int i = blockIdx.x*256 + threadIdx.x;
  if (i < n) p[i] = 0.f;
}

// ---------------- KNN phase A: per-point top-20 over a j-stripe (4 stripes) ----------------
__global__ __launch_bounds__(256) void knnA_kernel(const float* __restrict__ x,
                                                   float* __restrict__ pv, int* __restrict__ pi){
#pragma clang fp contract(off)
  __shared__ float4 p4[1024];
  int blk = blockIdx.x;
  int stripe = blk & 3;
  int chunk  = (blk >> 2) & 15;
  int b      = blk >> 6;
  const float* xb = x + b*3*Nn;
  int j0 = stripe*1024;
  for (int u = threadIdx.x; u < 1024; u += 256){
    int j = j0 + u;
    float a0 = xb[j];
    float a1 = xb[Nn + j];
    float a2 = xb[2*Nn + j];
    float s = a0*a0; s = s + a1*a1; s = s + a2*a2;   // xx = ((x^2)+(y^2))+(z^2)
    p4[u] = make_float4(a0, a1, a2, s);
  }
  __syncthreads();
  int i = chunk*256 + threadIdx.x;
  float xi = xb[i], yi = xb[Nn+i], zi = xb[2*Nn+i];
  float ni = xi*xi; ni = ni + yi*yi; ni = ni + zi*zi;
  float mni = -ni;
  float tv[Kk]; int ti[Kk];
  #pragma unroll
  for (int s=0;s<Kk;++s){ tv[s] = -FLT_MAX; ti[s] = 0; }
  for (int u=0; u<1024; ++u){
    float4 p = p4[u];
    float dot = xi*p.x; dot = dot + yi*p.y; dot = dot + zi*p.z;
    float inner = -2.0f*dot;
    float nd = mni - inner; nd = nd - p.w;            // (-xx_i - inner) - xx_j
    if (nd > tv[Kk-1]){
      #pragma unroll
      for (int s=Kk-1; s>=1; --s){
        bool cs = nd > tv[s];
        bool cp = nd > tv[s-1];
        tv[s] = cs ? (cp ? tv[s-1] : nd) : tv[s];
        ti[s] = cs ? (cp ? ti[s-1] : (j0+u)) : ti[s];
      }
      if (nd > tv[0]){ tv[0] = nd; ti[0] = j0+u; }
    }
  }
  long long base = ((long long)(b*Nn + i)*4 + stripe)*Kk;
  #pragma unroll
  for (int s=0;s<Kk;++s){ pv[base+s] = tv[s]; pi[base+s] = ti[s]; }
}

// ---------------- KNN phase B: merge the four stripe lists ----------------
__global__ __launch_bounds__(256) void knnB_kernel(const float* __restrict__ pv,
                                                   const int* __restrict__ pi,
                                                   int* __restrict__ idx){
  int p = blockIdx.x*256 + threadIdx.x;
  if (p >= BN) return;
  long long base = (long long)p*4*Kk;
  float av[Kk]; int ai[Kk];
  #pragma unroll
  for (int s=0;s<Kk;++s){ av[s]=pv[base+s]; ai[s]=pi[base+s]; }
  for (int t=Kk; t<4*Kk; ++t){
    float nd = pv[base+t]; int j = pi[base+t];
    if (nd > av[Kk-1]){
      #pragma unroll
      for (int s=Kk-1;s>=1;--s){
        bool cs = nd > av[s];
        bool cp = nd > av[s-1];
        av[s] = cs ? (cp?av[s-1]:nd) : av[s];
        ai[s] = cs ? (cp?ai[s-1]:j) : ai[s];
      }
      if (nd > av[0]){ av[0]=nd; ai[0]=j; }
    }
  }
  #pragma unroll
  for (int s=0;s<Kk;++s) idx[(long long)p*Kk+s] = ai[s];
}

// ---------------- layer-1 feature stats: sum(f) and f^T f (6x6) ----------------
__global__ __launch_bounds__(256) void gramf_kernel(const float* __restrict__ x,
                                                    const int* __restrict__ idx,
                                                    float* __restrict__ part){
  float acc[36]; float s6[6];
  #pragma unroll
  for (int a=0;a<36;++a) acc[a]=0.f;
  #pragma unroll
  for (int a=0;a<6;++a) s6[a]=0.f;
  for (long long row = blockIdx.x*256 + threadIdx.x; row < Mrows; row += (long long)gridDim.x*256){
    int bn = (int)(row / Kk);
    int b = bn >> 12, n = bn & 4095;
    int j = idx[row];
    const float* xb = x + b*3*Nn;
    float f[6];
    f[0]=xb[j];  f[1]=xb[Nn+j];  f[2]=xb[2*Nn+j];
    f[3]=xb[n];  f[4]=xb[Nn+n];  f[5]=xb[2*Nn+n];
    #pragma unroll
    for (int a=0;a<6;++a){
      s6[a] += f[a];
      #pragma unroll
      for (int c=0;c<6;++c) acc[a*6+c] = fmaf(f[a], f[c], acc[a*6+c]);
    }
  }
  __shared__ float red[256];
  for (int v=0; v<42; ++v){
    red[threadIdx.x] = (v<36)? acc[v] : s6[v-36];
    __syncthreads();
    for (int s=128; s>0; s>>=1){
      if (threadIdx.x < s) red[threadIdx.x] += red[threadIdx.x+s];
      __syncthreads();
    }
    if (threadIdx.x==0) part[blockIdx.x*48 + v] = red[0];
    __syncthreads();
  }
}

__global__ void reducef_kernel(const float* __restrict__ part, float* __restrict__ Gf,
                               float* __restrict__ sumf){
  int t = threadIdx.x;
  if (t < 42){
    float s = 0.f;
    for (int i=0;i<256;++i) s += part[i*48 + t];
    if (t<36) Gf[t]=s; else sumf[t-36]=s;
  }
}

// ---------------- Gram: G = H^T H, 64x64 tiles ----------------
template<int CIN, typename T>
__global__ __launch_bounds__(256) void gram_kernel(const T* __restrict__ H, int M,
                                                   float* __restrict__ G){
  constexpr int Tt = CIN/64;
  int tile = blockIdx.x % (Tt*Tt);
  int chunk = blockIdx.x / (Tt*Tt);
  int nchunks = gridDim.x / (Tt*Tt);
  int tr = tile / Tt, tc = tile % Tt;
  __shared__ float Aw[16][64];
  __shared__ float Bw[16][64];
  int rpc = (M + nchunks - 1)/nchunks;
  int r0 = chunk*rpc; int r1 = min(M, r0+rpc);
  int tx = threadIdx.x & 15, ty = threadIdx.x >> 4;
  float acc[4][4] = {};
  for (int rb=r0; rb<r1; rb+=16){
    int nr = min(16, r1-rb);
    for (int u=threadIdx.x; u<1024; u+=256){
      int rr = u >> 6, cc = u & 63;
      float av=0.f, bv=0.f;
      if (rr < nr){
        const T* hp = H + (size_t)(rb+rr)*CIN;
        av = ldf(hp[tr*64+cc]);
        bv = ldf(hp[tc*64+cc]);
      }
      Aw[rr][cc]=av; Bw[rr][cc]=bv;
    }
    __syncthreads();
    for (int r=0;r<nr;++r){
      float4 af = *(const float4*)&Aw[r][ty*4];
      float4 bf = *(const float4*)&Bw[r][tx*4];
      float a[4] = {af.x, af.y, af.z, af.w};
      float bq[4] = {bf.x, bf.y, bf.z, bf.w};
      #pragma unroll
      for (int u=0;u<4;++u)
        #pragma unroll
        for (int v=0;v<4;++v) acc[u][v] = fmaf(a[u], bq[v], acc[u][v]);
    }
    __syncthreads();
  }
  #pragma unroll
  for (int u=0;u<4;++u)
    #pragma unroll
    for (int v=0;v<4;++v)
      atomicAdd(&G[(size_t)(tr*64+ty*4+u)*CIN + (tc*64+tx*4+v)], acc[u][v]);
}

// ---------------- column sums of H ----------------
template<int CIN, typename T>
__global__ __launch_bounds__(256) void colsum_kernel(const T* __restrict__ H, int M,
                                                     float* __restrict__ sumh){
  int rpb = (M + gridDim.x - 1)/gridDim.x;
  int r0 = blockIdx.x*rpb, r1 = min(M, r0+rpb);
  if constexpr (CIN <= 256){
    constexpr int RP = 256/CIN;
    int c = threadIdx.x % CIN;
    int sub = threadIdx.x / CIN;
    float a = 0.f;
    for (int r=r0+sub; r<r1; r+=RP) a += ldf(H[(size_t)r*CIN + c]);
    atomicAdd(&sumh[c], a);
  } else {
    float a0=0.f, a1=0.f;
    for (int r=r0;r<r1;++r){
      a0 += ldf(H[(size_t)r*CIN + threadIdx.x]);
      a1 += ldf(H[(size_t)r*CIN + threadIdx.x + 256]);
    }
    atomicAdd(&sumh[threadIdx.x], a0);
    atomicAdd(&sumh[threadIdx.x+256], a1);
  }
}

// ---------------- P = G @ W ----------------
__global__ void kP_kernel(const float* __restrict__ G, const float* __restrict__ Wf,
                          float* __restrict__ P, int Cin, int Cout){
  int id = blockIdx.x*256 + threadIdx.x;
  if (id >= Cin*Cout) return;
  int i = id / Cout, j = id - i*Cout;
  float s = 0.f;
  for (int k=0;k<Cin;++k) s = fmaf(G[(size_t)i*Cin+k], Wf[(size_t)k*Cout+j], s);
  P[id] = s;
}

// ---------------- scale/shift from Gram-derived BN stats ----------------
__global__ void kFinal_kernel(const float* __restrict__ P, const float* __restrict__ sumh,
                              const float* __restrict__ Wf, const float* __restrict__ g,
                              const float* __restrict__ bb, float* __restrict__ scale,
                              float* __restrict__ shift, int Cin, int Cout, float invM){
  int j = blockIdx.x*256 + threadIdx.x;
  if (j >= Cout) return;
  float mean=0.f, e2=0.f;
  for (int i=0;i<Cin;++i){
    float w = Wf[(size_t)i*Cout + j];
    mean = fmaf(sumh[i], w, mean);
    e2   = fmaf(w, P[(size_t)i*Cout + j], e2);
  }
  mean *= invM; e2 *= invM;
  float var = e2 - mean*mean;
  float inv = rsqrtf(var + EPSf);
  float sc = g[j]*inv;
  scale[j]=sc;
  shift[j]=bb[j] - mean*sc;
}

// ---------------- layer-2 stats: on-the-fly H1 -> Gram2(64x64) + colsum2 ----------------
__global__ __launch_bounds__(256) void stats2_kernel(const float* __restrict__ x,
    const int* __restrict__ idx, const float* __restrict__ W1f,
    const float* __restrict__ sc1v, const float* __restrict__ sh1v,
    float* __restrict__ G2, float* __restrict__ sum2){
  __shared__ float W1s[6][64];
  __shared__ float fsh[16][6];
  __shared__ float Aw[16][64];
  __shared__ float scs[64], shs[64];
  int tid = threadIdx.x;
  for (int u=tid; u<384; u+=256) W1s[u/64][u%64] = W1f[u];
  if (tid < 64){ scs[tid]=sc1v[tid]; shs[tid]=sh1v[tid]; }
  __syncthreads();
  int rpc = (Mrows + gridDim.x - 1)/gridDim.x;
  int r0 = blockIdx.x*rpc, r1 = min(Mrows, r0+rpc);
  int ty = tid >> 4, tx = tid & 15;
  int myc = tid & 63;
  float acc[4][4] = {};
  float cs = 0.f;
  for (int rb=r0; rb<r1; rb+=16){
    if (tid < 16){
      int row = rb + tid;
      float f0=0,f1=0,f2=0,f3=0,f4=0,f5=0;
      if (row < r1){
        int bn = row / Kk;
        int b = bn >> 12, n = bn & 4095;
        int j = idx[row];
        const float* xb = x + b*3*Nn;
        f0=xb[j]; f1=xb[Nn+j]; f2=xb[2*Nn+j];
        f3=xb[n]; f4=xb[Nn+n]; f5=xb[2*Nn+n];
      }
      fsh[tid][0]=f0; fsh[tid][1]=f1; fsh[tid][2]=f2;
      fsh[tid][3]=f3; fsh[tid][4]=f4; fsh[tid][5]=f5;
    }
    __syncthreads();
    #pragma unroll
    for (int k=0;k<4;++k){
      int rr = (tid>>6) + k*4;
      float y = 0.f;
      #pragma unroll
      for (int i=0;i<6;++i) y = fmaf(fsh[rr][i], W1s[i][myc], y);
      float v = fmaxf(fmaf(y, scs[myc], shs[myc]), 0.f);
      if (rb + rr >= r1) v = 0.f;
      Aw[rr][myc] = v;
      cs += v;
    }
    __syncthreads();
    for (int r=0;r<16;++r){
      float4 af = *(const float4*)&Aw[r][ty*4];
      float4 bf = *(const float4*)&Aw[r][tx*4];
      float a[4] = {af.x, af.y, af.z, af.w};
      float bq[4] = {bf.x, bf.y, bf.z, bf.w};
      #pragma unroll
      for (int u=0;u<4;++u)
        #pragma unroll
        for (int v=0;v<4;++v) acc[u][v]=fmaf(a[u],bq[v],acc[u][v]);
    }
    __syncthreads();
  }
  #pragma unroll
  for (int u=0;u<4;++u)
    #pragma unroll
    for (int v=0;v<4;++v)
      atomicAdd(&G2[(size_t)(ty*4+u)*64 + tx*4+v], acc[u][v]);
  atomicAdd(&sum2[myc], cs);
}

// ---------------- fused layers 1+2: gather->H1->x1, H1@W2 -> H2(bf16) + x2 ----------------
__global__ __launch_bounds__(64) void fl12_kernel(const float* __restrict__ x,
    const int* __restrict__ idx, const float* __restrict__ W1f,
    const float* __restrict__ sc1v, const float* __restrict__ sh1v,
    const float* __restrict__ W2f, const float* __restrict__ sc2v,
    const float* __restrict__ sh2v, bf16* __restrict__ H2, bf16* __restrict__ cat){
  __shared__ float fsh[Kk][6];
  __shared__ float h1[Kk][64];
  __shared__ float mm[4][64];
  int bn = blockIdx.x, b = bn>>12, n = bn & 4095;
  int tid = threadIdx.x;
  if (tid < Kk){
    int j = idx[(size_t)bn*Kk + tid];
    const float* xb = x + b*3*Nn;
    fsh[tid][0]=xb[j]; fsh[tid][1]=xb[Nn+j]; fsh[tid][2]=xb[2*Nn+j];
    fsh[tid][3]=xb[n]; fsh[tid][4]=xb[Nn+n]; fsh[tid][5]=xb[2*Nn+n];
  }
  __syncthreads();
  {
    float sc=sc1v[tid], sh=sh1v[tid];
    float w[6];
    #pragma unroll
    for (int i=0;i<6;++i) w[i]=W1f[i*64+tid];
    float mx = 0.f;
    #pragma unroll
    for (int r=0;r<Kk;++r){
      float y=0.f;
      #pragma unroll
      for (int i=0;i<6;++i) y = fmaf(fsh[r][i], w[i], y);
      float v = fmaxf(fmaf(y,sc,sh),0.f);
      h1[r][tid]=v;
      mx = fmaxf(mx,v);
    }
    cat[(size_t)bn*512 + tid] = f2b(mx);
  }
  __syncthreads();
  int q = tid >> 4, c0 = (tid & 15)*4;
  float acc[5][4]={};
  for (int i0=0;i0<64;i0+=4){
    float hv[5][4];
    #pragma unroll
    for (int l=0;l<5;++l){
      float4 t4 = *(const float4*)&h1[q*5+l][i0];
      hv[l][0]=t4.x; hv[l][1]=t4.y; hv[l][2]=t4.z; hv[l][3]=t4.w;
    }
    #pragma unroll
    for (int ii=0;ii<4;++ii){
      const float* wp = W2f + (i0+ii)*64 + c0;
      float w0=wp[0],w1=wp[1],w2=wp[2],w3=wp[3];
      #pragma unroll
      for (int l=0;l<5;++l){
        float hvv=hv[l][ii];
        acc[l][0]=fmaf(hvv,w0,acc[l][0]);
        acc[l][1]=fmaf(hvv,w1,acc[l][1]);
        acc[l][2]=fmaf(hvv,w2,acc[l][2]);
        acc[l][3]=fmaf(hvv,w3,acc[l][3]);
      }
    }
  }
  float sc[4],sh[4];
  #pragma unroll
  for (int cb=0;cb<4;++cb){ sc[cb]=sc2v[c0+cb]; sh[cb]=sh2v[c0+cb]; }
  float mx[4]={0,0,0,0};
  #pragma unroll
  for (int l=0;l<5;++l){
    unsigned short us[4];
    #pragma unroll
    for (int cb=0;cb<4;++cb){
      float v=fmaxf(fmaf(acc[l][cb],sc[cb],sh[cb]),0.f);
      mx[cb]=fmaxf(mx[cb],v);
      us[cb]=f2bu(v);
    }
    uint2 v2; v2.x = us[0]|((unsigned)us[1]<<16); v2.y=us[2]|((unsigned)us[3]<<16);
    *(uint2*)(H2 + ((size_t)bn*Kk + q*5+l)*64 + c0) = v2;
  }
  #pragma unroll
  for (int cb=0;cb<4;++cb) mm[q][c0+cb]=mx[cb];
  __syncthreads();
  {
    float M0 = fmaxf(fmaxf(mm[0][tid],mm[1][tid]),fmaxf(mm[2][tid],mm[3][tid]));
    cat[(size_t)bn*512 + 64 + tid] = f2b(M0);
  }
}

// ---------------- layer-4 stats: on-the-fly H3 -> Gram4(128x128) + colsum4 ----------------
// 512 threads, acc[8][4]=32 regs/thread (spill-proof). All strided LDS float4
// arrays granule-XOR-swizzled (W3s + h3s) -> conflict-free b128 reads.
__global__ __launch_bounds__(512) void stats4_kernel(const bf16* __restrict__ H2,
    const float* __restrict__ W3f, const float* __restrict__ sc3v, const float* __restrict__ sh3v,
    float* __restrict__ G4, float* __restrict__ sum4){
  __shared__ float W3s[64*128];   // swizzled granules
  __shared__ float h2s[16][64];
  __shared__ float h3s[16*128];   // swizzled granules
  int tid = threadIdx.x;
  for (int u=tid; u<8192; u+=512){
    int i = u>>7, c = u&127;
    W3s[i*128 + sw4(c>>2)*4 + (c&3)] = W3f[u];
  }
  __syncthreads();
  int rpc=(Mrows+gridDim.x-1)/gridDim.x;
  int r0=blockIdx.x*rpc, r1=min(Mrows,r0+rpc);
  int rr = tid>>5, cg = tid&31;          // produce: row rr, cols 4cg..4cg+3
  int wrg = sw4(cg)*4;
  int ty = tid>>5, tx = tid&31;          // gram: rows ty*8..+7, cols tx*4..+3
  int ga0 = sw4(2*ty)*4, ga1 = sw4(2*ty+1)*4, gb = sw4(tx)*4;
  float acc[8][4]={};
  float cs[4]={0.f,0.f,0.f,0.f};
  float sca[4], sha[4];
  #pragma unroll
  for (int k=0;k<4;++k){ sca[k]=sc3v[cg*4+k]; sha[k]=sh3v[cg*4+k]; }
  for (int rb=r0; rb<r1; rb+=16){
    for (int u=tid; u<1024; u+=512){
      int r2=u>>6, cc=u&63;
      float v=0.f;
      int row=rb+r2;
      if (row<r1) v=b2f(H2[(size_t)row*64+cc]);
      h2s[r2][cc]=v;
    }
    __syncthreads();
    // produce h3s: 1 row x 4 cols per thread, i-ascending (bit-identical to fl34)
    {
      float y[4]={0,0,0,0};
      for (int i=0;i<64;++i){
        float4 w = *(const float4*)&W3s[i*128 + wrg];
        float ha = h2s[rr][i];
        y[0]=fmaf(ha,w.x,y[0]); y[1]=fmaf(ha,w.y,y[1]);
        y[2]=fmaf(ha,w.z,y[2]); y[3]=fmaf(ha,w.w,y[3]);
      }
      bool ok = (rb+rr < r1);
      float va[4];
      #pragma unroll
      for (int k=0;k<4;++k){
        float v0 = fmaxf(fmaf(y[k],sca[k],sha[k]),0.f);
        va[k] = ok ? v0 : 0.f;
        cs[k] += va[k];
      }
      *(float4*)&h3s[rr*128 + wrg] = make_float4(va[0],va[1],va[2],va[3]);
    }
    __syncthreads();
    for (int r=0;r<16;++r){
      const float* hr = &h3s[r*128];
      float4 a0 = *(const float4*)&hr[ga0];
      float4 a1 = *(const float4*)&hr[ga1];
      float4 b0 = *(const float4*)&hr[gb];
      float a[8] = {a0.x,a0.y,a0.z,a0.w,a1.x,a1.y,a1.z,a1.w};
      float bq[4] = {b0.x,b0.y,b0.z,b0.w};
      #pragma unroll
      for (int u=0;u<8;++u)
        #pragma unroll
        for (int v=0;v<4;++v) acc[u][v]=fmaf(a[u],bq[v],acc[u][v]);
    }
    __syncthreads();
  }
  #pragma unroll
  for (int u=0;u<8;++u)
    #pragma unroll
    for (int v=0;v<4;++v)
      atomicAdd(&G4[(size_t)(ty*8+u)*128 + tx*4+v], acc[u][v]);
  #pragma unroll
  for (int k=0;k<4;++k) atomicAdd(&sum4[cg*4+k], cs[k]);
}

// ---------------- fused layers 3+4: 4 points/block. H2->H3->x3, H3@W4->x4 ----------------
__global__ __launch_bounds__(512,2) void fl34_kernel(const bf16* __restrict__ H2,
    const float* __restrict__ W3f, const float* __restrict__ sc3v, const float* __restrict__ sh3v,
    const float* __restrict__ W4f, const float* __restrict__ sc4v, const float* __restrict__ sh4v,
    bf16* __restrict__ cat){
  __shared__ float h2s[4][Kk][64];      // 20 KB
  __shared__ float h3s[4][Kk][128];     // 40 KB
  __shared__ float w4s[16][256];        // 16 KB, aliased as mm[4][4][256] after K-loop
  int tid = threadIdx.x;
  int bn0 = blockIdx.x*4;
  int pt = tid >> 7, tid2 = tid & 127;
  for (int u=tid; u<4*Kk*64; u+=512){
    int p = u / 1280, rem = u - p*1280;
    h2s[p][rem>>6][rem&63] = b2f(H2[((size_t)(bn0+p)*Kk + (rem>>6))*64 + (rem&63)]);
  }
  __syncthreads();
  // stage 1: H3 column tid2 for point pt, all 20 rows (i-ascending)
  {
    int c = tid2;
    float y[Kk];
    #pragma unroll
    for (int r=0;r<Kk;++r) y[r]=0.f;
    for (int i=0;i<64;++i){
      float w = W3f[i*128 + c];
      #pragma unroll
      for (int r=0;r<Kk;++r) y[r]=fmaf(h2s[pt][r][i], w, y[r]);
    }
    float sc=sc3v[c], sh=sh3v[c];
    float mx=0.f;
    #pragma unroll
    for (int r=0;r<Kk;++r){
      float v=fmaxf(fmaf(y[r],sc,sh),0.f);
      h3s[pt][r][c]=v;
      mx=fmaxf(mx,v);
    }
    cat[(size_t)(bn0+pt)*512 + 128 + c] = f2b(mx);
  }
  __syncthreads();
  // stage 2: Y4 = H3 @ W4; per point: 4 rowgroups(5) x 32 colgroups(8 strided)
  int q = tid2 >> 5, cbase = tid2 & 31;
  float acc[5][8]={};
  for (int i0=0;i0<128;i0+=16){
    for (int u=tid;u<4096;u+=512) w4s[u>>8][u&255]=W4f[(size_t)(i0+(u>>8))*256+(u&255)];
    __syncthreads();
    for (int ii=0;ii<16;++ii){
      float w[8];
      #pragma unroll
      for (int cb=0;cb<8;++cb) w[cb]=w4s[ii][cbase + cb*32];
      float hv[5];
      #pragma unroll
      for (int l=0;l<5;++l) hv[l]=h3s[pt][q*5+l][i0+ii];
      #pragma unroll
      for (int l=0;l<5;++l)
        #pragma unroll
        for (int cb=0;cb<8;++cb) acc[l][cb]=fmaf(hv[l],w[cb],acc[l][cb]);
    }
    __syncthreads();
  }
  float sc[8],sh[8];
  #pragma unroll
  for (int cb=0;cb<8;++cb){ sc[cb]=sc4v[cbase+cb*32]; sh[cb]=sh4v[cbase+cb*32]; }
  float mx[8];
  #pragma unroll
  for (int cb=0;cb<8;++cb) mx[cb]=0.f;
  #pragma unroll
  for (int l=0;l<5;++l)
    #pragma unroll
    for (int cb=0;cb<8;++cb){
      float v=fmaxf(fmaf(acc[l][cb],sc[cb],sh[cb]),0.f);
      mx[cb]=fmaxf(mx[cb],v);
    }
  float* mmf = &w4s[0][0];   // [4][4][256] alias (w4s dead after last sync)
  #pragma unroll
  for (int cb=0;cb<8;++cb) mmf[((pt*4+q)<<8) + cbase + cb*32] = mx[cb];
  __syncthreads();
  for (int u=tid; u<1024; u+=512){
    int p = u >> 8, c = u & 255;
    float M0 = fmaxf(fmaxf(mmf[((p*4+0)<<8)+c], mmf[((p*4+1)<<8)+c]),
                     fmaxf(mmf[((p*4+2)<<8)+c], mmf[((p*4+3)<<8)+c]));
    cat[(size_t)(bn0+p)*512 + 256 + c] = f2b(M0);
  }
}

// ---------------- layer 5: cat(bf16,512) @ W5, BN+ReLU, fp32 transposed store ----------------
__global__ __launch_bounds__(256) void l5_kernel(const bf16* __restrict__ cat,
                                                const float* __restrict__ Wf,
                                                const float* __restrict__ scale,
                                                const float* __restrict__ shift,
                                                float* __restrict__ out){
  __shared__ float cr[8][512];
  __shared__ float ob[8][512];
  int tid = threadIdx.x;
  int bn0 = blockIdx.x*8;
  for (int u=tid; u<8*512; u+=256) cr[u>>9][u&511] = b2f(cat[(size_t)bn0*512 + u]);
  __syncthreads();
  int rp = tid >> 6, cg = tid & 63, c0 = cg*8;
  int ra = rp*2, rb = rp*2+1;
  float acc[2][8] = {};
  for (int i=0;i<512;++i){
    float h0 = cr[ra][i], h1 = cr[rb][i];
    const float* wp = Wf + (size_t)i*512 + c0;
    float4 wa = *(const float4*)wp;
    float4 wb = *(const float4*)(wp+4);
    float w[8] = {wa.x,wa.y,wa.z,wa.w,wb.x,wb.y,wb.z,wb.w};
    #pragma unroll
    for (int k=0;k<8;++k){
      acc[0][k] = fmaf(h0, w[k], acc[0][k]);
      acc[1][k] = fmaf(h1, w[k], acc[1][k]);
    }
  }
  float sc[8], sh[8];
  #pragma unroll
  for (int k=0;k<8;++k){ sc[k]=scale[c0+k]; sh[k]=shift[c0+k]; }
  #pragma unroll
  for (int k=0;k<8;++k){
    ob[ra][c0+k] = fmaxf(fmaf(acc[0][k], sc[k], sh[k]), 0.f);
    ob[rb][c0+k] = fmaxf(fmaf(acc[1][k], sc[k], sh[k]), 0.f);
  }
  __syncthreads();
  int b = bn0 >> 12, n0 = bn0 & 4095;
  for (int u=tid; u<512; u+=256){
    float4 v0 = make_float4(ob[0][u], ob[1][u], ob[2][u], ob[3][u]);
    float4 v1 = make_float4(ob[4][u], ob[5][u], ob[6][u], ob[7][u]);
    float* op = out + ((size_t)b*512 + u)*4096 + n0;
    *(float4*)(op)   = v0;
    *(float4*)(op+4) = v1;
  }
}

extern "C" void kernel_launch(void* const* d_in, const int* in_sizes, int n_in,
                              void* d_out, int out_size, void* d_ws, size_t ws_size,
                              hipStream_t stream){
  const float* x   = (const float*)d_in[0];
  const float* W1f = (const float*)d_in[1];
  const float* W2f = (const float*)d_in[2];
  const float* W3f = (const float*)d_in[3];
  const float* W4f = (const float*)d_in[4];
  const float* W5f = (const float*)d_in[5];
  const float* g1=(const float*)d_in[6],  *b1=(const float*)d_in[7];
  const float* g2=(const float*)d_in[8],  *b2=(const float*)d_in[9];
  const float* g3=(const float*)d_in[10], *b3=(const float*)d_in[11];
  const float* g4=(const float*)d_in[12], *b4=(const float*)d_in[13];
  const float* g5=(const float*)d_in[14], *b5=(const float*)d_in[15];
  float* out = (float*)d_out;

  char* w = (char*)d_ws;
  size_t off = 0;
  auto alloc = [&](size_t bytes)->void*{
    void* p = w + off;
    off = (off + bytes + 255) & ~(size_t)255;
    return p;
  };

  int*  idxb = (int*) alloc((size_t)BN*Kk*4);          // 2.6 MB
  bf16* H2   = (bf16*)alloc((size_t)Mrows*64*2);       // 84 MB
  bf16* catb = (bf16*)alloc((size_t)BN*512*2);         // 33.6 MB
  // KNN scratch aliases H2 (H2 first written by fl12, after knnB is done)
  float* pv  = (float*)H2;                             // 10.5 MB
  int*   pib = (int*)((char*)H2 + (size_t)BN*4*Kk*4);  // 10.5 MB

  size_t statsStart = off;
  float* partf=(float*)alloc(256*48*4);
  float* Gf=(float*)alloc(36*4);
  float* sumf=(float*)alloc(8*4);
  float* G2=(float*)alloc(4096*4);   float* sum2=(float*)alloc(64*4);
  float* G3=(float*)alloc(4096*4);   float* sum3=(float*)alloc(64*4);
  float* G4=(float*)alloc(16384*4);  float* sum4=(float*)alloc(128*4);
  float* G5=(float*)alloc(262144*4); float* sum5=(float*)alloc(512*4);
  float* P1=(float*)alloc(384*4);
  float* P2=(float*)alloc(4096*4);
  float* P3=(float*)alloc(8192*4);
  float* P4=(float*)alloc(32768*4);
  float* P5=(float*)alloc(262144*4);
  float* sc1=(float*)alloc(64*4);   float* sh1=(float*)alloc(64*4);
  float* sc2=(float*)alloc(64*4);   float* sh2=(float*)alloc(64*4);
  float* sc3=(float*)alloc(128*4);  float* sh3=(float*)alloc(128*4);
  float* sc4=(float*)alloc(256*4);  float* sh4=(float*)alloc(256*4);
  float* sc5=(float*)alloc(512*4);  float* sh5=(float*)alloc(512*4);
  size_t statsEnd = off;

  int statsFloats = (int)((statsEnd - statsStart)/4);
  zero_kernel<<<(statsFloats+255)/256,256,0,stream>>>((float*)(w+statsStart), statsFloats);

  knnA_kernel<<<512,256,0,stream>>>(x, pv, pib);
  knnB_kernel<<<BN/256,256,0,stream>>>(pv, pib, idxb);

  const float invM  = 1.0f/(float)Mrows;
  const float invM5 = 1.0f/(float)BN;

  // layer 1 stats
  gramf_kernel<<<256,256,0,stream>>>(x, idxb, partf);
  reducef_kernel<<<1,64,0,stream>>>(partf, Gf, sumf);
  kP_kernel<<<2,256,0,stream>>>(Gf, W1f, P1, 6, 64);
  kFinal_kernel<<<1,256,0,stream>>>(P1, sumf, W1f, g1, b1, sc1, sh1, 6, 64, invM);

  // layer 2 stats (on-the-fly H1)
  stats2_kernel<<<2048,256,0,stream>>>(x, idxb, W1f, sc1, sh1, G2, sum2);
  kP_kernel<<<16,256,0,stream>>>(G2, W2f, P2, 64, 64);
  kFinal_kernel<<<1,256,0,stream>>>(P2, sum2, W2f, g2, b2, sc2, sh2, 64, 64, invM);

  // apply layers 1+2
  fl12_kernel<<<BN,64,0,stream>>>(x, idxb, W1f, sc1, sh1, W2f, sc2, sh2, H2, catb);

  // layer 3 stats from H2
  colsum_kernel<64,bf16><<<512,256,0,stream>>>(H2, Mrows, sum3);
  gram_kernel<64,bf16><<<2048,256,0,stream>>>(H2, Mrows, G3);
  kP_kernel<<<32,256,0,stream>>>(G3, W3f, P3, 64, 128);
  kFinal_kernel<<<1,256,0,stream>>>(P3, sum3, W3f, g3, b3, sc3, sh3, 64, 128, invM);

  // layer 4 stats (on-the-fly H3)
  stats4_kernel<<<512,512,0,stream>>>(H2, W3f, sc3, sh3, G4, sum4);
  kP_kernel<<<128,256,0,stream>>>(G4, W4f, P4, 128, 256);
  kFinal_kernel<<<1,256,0,stream>>>(P4, sum4, W4f, g4, b4, sc4, sh4, 128, 256, invM);

  // apply layers 3+4 (4 points per block)
  fl34_kernel<<<BN/4,512,0,stream>>>(H2, W3f, sc3, sh3, W4f, sc4, sh4, catb);

  // layer 5
  colsum_kernel<512,bf16><<<512,256,0,stream>>>(catb, BN, sum5);
  gram_kernel<512,bf16><<<2048,256,0,stream>>>(catb, BN, G5);
  kP_kernel<<<1024,256,0,stream>>>(G5, W5f, P5, 512, 512);
  kFinal_kernel<<<2,256,0,stream>>>(P5, sum5, W5f, g5, b5, sc5, sh5, 512, 512, invM5);
  l5_kernel<<<BN/8,256,0,stream>>>(catb, W5f, sc5, sh5, out);
}

// Round 7
// 4366.286 us; speedup vs baseline: 1.3937x; 1.1630x over previous
//
#include <hip/hip_runtime.h>
#include <hip/hip_bf16.h>
#include <cfloat>

using bf16 = __hip_bfloat16;

typedef short short8 __attribute__((ext_vector_type(8)));
typedef float floatx16 __attribute__((ext_vector_type(16)));
union Frag { short8 v; uint2 u2[2]; };
union U4b { uint4 q; unsigned short s[8]; };

constexpr int Bb = 8, Nn = 4096, Kk = 20;
constexpr int BN = Bb * Nn;                     // 32768
constexpr int Mrows = BN * Kk;                  // 655360
constexpr float EPSf = 1e-5f;

static __device__ __forceinline__ float b2f(bf16 v){ return __bfloat162float(v); }
static __device__ __forceinline__ bf16 f2b(float v){ return __float2bfloat16(v); }
static __device__ __forceinline__ unsigned short f2bu(float v){
  union { bf16 b; unsigned short u; } cv; cv.b = __float2bfloat16(v); return cv.u;
}
static __device__ __forceinline__ float bits2f(unsigned short u){
  union { unsigned int i; float f; } c; c.i = ((unsigned)u)<<16; return c.f;
}
static __device__ __forceinline__ float ldf(bf16 v){ return b2f(v); }
static __device__ __forceinline__ float ldf(float v){ return v; }
// float4-granule XOR swizzle: 32 granules -> distinct bank-groups for strided reads
static __device__ __forceinline__ int sw4(int g){ return g ^ (g >> 3); }

// ---------------- zero workspace region ----------------
__global__ void zero_kernel(float* __restrict__ p, int n){
  int i = blockIdx.x*256 + threadIdx.x;
  if (i < n) p[i] = 0.f;
}

// ---------------- KNN phase A: per-point top-20 over a j-stripe (4 stripes) ----------------
__global__ __launch_bounds__(256) void knnA_kernel(const float* __restrict__ x,
                                                   float* __restrict__ pv, int* __restrict__ pi){
#pragma clang fp contract(off)
  __shared__ float4 p4[1024];
  int blk = blockIdx.x;
  int stripe = blk & 3;
  int chunk  = (blk >> 2) & 15;
  int b      = blk >> 6;
  const float* xb = x + b*3*Nn;
  int j0 = stripe*1024;
  for (int u = threadIdx.x; u < 1024; u += 256){
    int j = j0 + u;
    float a0 = xb[j];
    float a1 = xb[Nn + j];
    float a2 = xb[2*Nn + j];
    float s = a0*a0; s = s + a1*a1; s = s + a2*a2;
    p4[u] = make_float4(a0, a1, a2, s);
  }
  __syncthreads();
  int i = chunk*256 + threadIdx.x;
  float xi = xb[i], yi = xb[Nn+i], zi = xb[2*Nn+i];
  float ni = xi*xi; ni = ni + yi*yi; ni = ni + zi*zi;
  float mni = -ni;
  float tv[Kk]; int ti[Kk];
  #pragma unroll
  for (int s=0;s<Kk;++s){ tv[s] = -FLT_MAX; ti[s] = 0; }
  for (int u=0; u<1024; ++u){
    float4 p = p4[u];
    float dot = xi*p.x; dot = dot + yi*p.y; dot = dot + zi*p.z;
    float inner = -2.0f*dot;
    float nd = mni - inner; nd = nd - p.w;
    if (nd > tv[Kk-1]){
      #pragma unroll
      for (int s=Kk-1; s>=1; --s){
        bool cs = nd > tv[s];
        bool cp = nd > tv[s-1];
        tv[s] = cs ? (cp ? tv[s-1] : nd) : tv[s];
        ti[s] = cs ? (cp ? ti[s-1] : (j0+u)) : ti[s];
      }
      if (nd > tv[0]){ tv[0] = nd; ti[0] = j0+u; }
    }
  }
  long long base = ((long long)(b*Nn + i)*4 + stripe)*Kk;
  #pragma unroll
  for (int s=0;s<Kk;++s){ pv[base+s] = tv[s]; pi[base+s] = ti[s]; }
}

// ---------------- KNN phase B: merge the four stripe lists ----------------
__global__ __launch_bounds__(256) void knnB_kernel(const float* __restrict__ pv,
                                                   const int* __restrict__ pi,
                                                   int* __restrict__ idx){
  int p = blockIdx.x*256 + threadIdx.x;
  if (p >= BN) return;
  long long base = (long long)p*4*Kk;
  float av[Kk]; int ai[Kk];
  #pragma unroll
  for (int s=0;s<Kk;++s){ av[s]=pv[base+s]; ai[s]=pi[base+s]; }
  for (int t=Kk; t<4*Kk; ++t){
    float nd = pv[base+t]; int j = pi[base+t];
    if (nd > av[Kk-1]){
      #pragma unroll
      for (int s=Kk-1;s>=1;--s){
        bool cs = nd > av[s];
        bool cp = nd > av[s-1];
        av[s] = cs ? (cp?av[s-1]:nd) : av[s];
        ai[s] = cs ? (cp?ai[s-1]:j) : ai[s];
      }
      if (nd > av[0]){ av[0]=nd; ai[0]=j; }
    }
  }
  #pragma unroll
  for (int s=0;s<Kk;++s) idx[(long long)p*Kk+s] = ai[s];
}

// ---------------- layer-1 feature stats: sum(f) and f^T f (6x6) ----------------
__global__ __launch_bounds__(256) void gramf_kernel(const float* __restrict__ x,
                                                    const int* __restrict__ idx,
                                                    float* __restrict__ part){
  float acc[36]; float s6[6];
  #pragma unroll
  for (int a=0;a<36;++a) acc[a]=0.f;
  #pragma unroll
  for (int a=0;a<6;++a) s6[a]=0.f;
  for (long long row = blockIdx.x*256 + threadIdx.x; row < Mrows; row += (long long)gridDim.x*256){
    int bn = (int)(row / Kk);
    int b = bn >> 12, n = bn & 4095;
    int j = idx[row];
    const float* xb = x + b*3*Nn;
    float f[6];
    f[0]=xb[j];  f[1]=xb[Nn+j];  f[2]=xb[2*Nn+j];
    f[3]=xb[n];  f[4]=xb[Nn+n];  f[5]=xb[2*Nn+n];
    #pragma unroll
    for (int a=0;a<6;++a){
      s6[a] += f[a];
      #pragma unroll
      for (int c=0;c<6;++c) acc[a*6+c] = fmaf(f[a], f[c], acc[a*6+c]);
    }
  }
  __shared__ float red[256];
  for (int v=0; v<42; ++v){
    red[threadIdx.x] = (v<36)? acc[v] : s6[v-36];
    __syncthreads();
    for (int s=128; s>0; s>>=1){
      if (threadIdx.x < s) red[threadIdx.x] += red[threadIdx.x+s];
      __syncthreads();
    }
    if (threadIdx.x==0) part[blockIdx.x*48 + v] = red[0];
    __syncthreads();
  }
}

__global__ void reducef_kernel(const float* __restrict__ part, float* __restrict__ Gf,
                               float* __restrict__ sumf){
  int t = threadIdx.x;
  if (t < 42){
    float s = 0.f;
    for (int i=0;i<256;++i) s += part[i*48 + t];
    if (t<36) Gf[t]=s; else sumf[t-36]=s;
  }
}

// ---------------- MFMA Gram: G = H^T H over bf16 H (products bit-exact) ----------------
// 64x64 G-tiles; 64-row K-chunks staged transposed (HT[64][68] bf16, 2-way-free b64 reads).
template<int CIN>
__global__ __launch_bounds__(256) void gramM_kernel(const bf16* __restrict__ H, int M,
                                                    float* __restrict__ G){
  constexpr int Tt = CIN/64;
  int tile = blockIdx.x % (Tt*Tt);
  int chunk = blockIdx.x / (Tt*Tt);
  int nchunks = gridDim.x / (Tt*Tt);
  int tr = tile / Tt, tc = tile % Tt;
  bool diag = (tr == tc);
  __shared__ short HTa[64*68];
  __shared__ short HTb[64*68];
  int rpc = M / nchunks;               // multiple of 64 by construction
  int r0 = chunk*rpc;
  int tid = threadIdx.x, lane = tid & 63, w = tid >> 6;   // 4 waves
  int mt = w >> 1, nt = w & 1;
  floatx16 acc;
  #pragma unroll
  for (int q=0;q<16;++q) acc[q]=0.f;
  const short* Bbase = diag ? HTa : HTb;
  int arow = (mt*32 + (lane&31))*68;
  int brow = (nt*32 + (lane&31))*68;
  int ko = (lane>>5)*8;
  for (int rb=r0; rb<r0+rpc; rb+=64){
    // stage slice tr (and tc) transposed
    #pragma unroll
    for (int s=0;s<2;++s){
      int e = tid + s*256;
      int row = e >> 3, c0 = (e & 7)*8;
      U4b va; va.q = *(const uint4*)&H[(size_t)(rb+row)*CIN + tr*64 + c0];
      #pragma unroll
      for (int j=0;j<8;++j) HTa[(c0+j)*68 + row] = (short)va.s[j];
      if (!diag){
        U4b vb; vb.q = *(const uint4*)&H[(size_t)(rb+row)*CIN + tc*64 + c0];
        #pragma unroll
        for (int j=0;j<8;++j) HTb[(c0+j)*68 + row] = (short)vb.s[j];
      }
    }
    __syncthreads();
    #pragma unroll
    for (int kc=0;kc<64;kc+=16){
      Frag a, b;
      const short* ap = &HTa[arow + kc + ko];
      const short* bp = &Bbase[brow + kc + ko];
      a.u2[0] = *(const uint2*)ap;  a.u2[1] = *(const uint2*)(ap+4);
      b.u2[0] = *(const uint2*)bp;  b.u2[1] = *(const uint2*)(bp+4);
      acc = __builtin_amdgcn_mfma_f32_32x32x16_bf16(a.v, b.v, acc, 0, 0, 0);
    }
    __syncthreads();
  }
  int col = lane & 31, rbase = 4*(lane>>5);
  #pragma unroll
  for (int r=0;r<16;++r){
    int row = (r&3) + 8*(r>>2) + rbase;
    atomicAdd(&G[(size_t)(tr*64 + mt*32 + row)*CIN + tc*64 + nt*32 + col], acc[r]);
  }
}

// ---------------- column sums of H ----------------
template<int CIN, typename T>
__global__ __launch_bounds__(256) void colsum_kernel(const T* __restrict__ H, int M,
                                                     float* __restrict__ sumh){
  int rpb = (M + gridDim.x - 1)/gridDim.x;
  int r0 = blockIdx.x*rpb, r1 = min(M, r0+rpb);
  if constexpr (CIN <= 256){
    constexpr int RP = 256/CIN;
    int c = threadIdx.x % CIN;
    int sub = threadIdx.x / CIN;
    float a = 0.f;
    for (int r=r0+sub; r<r1; r+=RP) a += ldf(H[(size_t)r*CIN + c]);
    atomicAdd(&sumh[c], a);
  } else {
    float a0=0.f, a1=0.f;
    for (int r=r0;r<r1;++r){
      a0 += ldf(H[(size_t)r*CIN + threadIdx.x]);
      a1 += ldf(H[(size_t)r*CIN + threadIdx.x + 256]);
    }
    atomicAdd(&sumh[threadIdx.x], a0);
    atomicAdd(&sumh[threadIdx.x+256], a1);
  }
}

// ---------------- P = G @ W ----------------
__global__ void kP_kernel(const float* __restrict__ G, const float* __restrict__ Wf,
                          float* __restrict__ P, int Cin, int Cout){
  int id = blockIdx.x*256 + threadIdx.x;
  if (id >= Cin*Cout) return;
  int i = id / Cout, j = id - i*Cout;
  float s = 0.f;
  for (int k=0;k<Cin;++k) s = fmaf(G[(size_t)i*Cin+k], Wf[(size_t)k*Cout+j], s);
  P[id] = s;
}

// ---------------- scale/shift from Gram-derived BN stats ----------------
__global__ void kFinal_kernel(const float* __restrict__ P, const float* __restrict__ sumh,
                              const float* __restrict__ Wf, const float* __restrict__ g,
                              const float* __restrict__ bb, float* __restrict__ scale,
                              float* __restrict__ shift, int Cin, int Cout, float invM){
  int j = blockIdx.x*256 + threadIdx.x;
  if (j >= Cout) return;
  float mean=0.f, e2=0.f;
  for (int i=0;i<Cin;++i){
    float w = Wf[(size_t)i*Cout + j];
    mean = fmaf(sumh[i], w, mean);
    e2   = fmaf(w, P[(size_t)i*Cout + j], e2);
  }
  mean *= invM; e2 *= invM;
  float var = e2 - mean*mean;
  float inv = rsqrtf(var + EPSf);
  float sc = g[j]*inv;
  scale[j]=sc;
  shift[j]=bb[j] - mean*sc;
}

// ---------------- layer-2 stats: on-the-fly H1 -> Gram2(64x64) + colsum2 ----------------
__global__ __launch_bounds__(256) void stats2_kernel(const float* __restrict__ x,
    const int* __restrict__ idx, const float* __restrict__ W1f,
    const float* __restrict__ sc1v, const float* __restrict__ sh1v,
    float* __restrict__ G2, float* __restrict__ sum2){
  __shared__ float W1s[6][64];
  __shared__ float fsh[16][6];
  __shared__ float Aw[16][64];
  __shared__ float scs[64], shs[64];
  int tid = threadIdx.x;
  for (int u=tid; u<384; u+=256) W1s[u/64][u%64] = W1f[u];
  if (tid < 64){ scs[tid]=sc1v[tid]; shs[tid]=sh1v[tid]; }
  __syncthreads();
  int rpc = (Mrows + gridDim.x - 1)/gridDim.x;
  int r0 = blockIdx.x*rpc, r1 = min(Mrows, r0+rpc);
  int ty = tid >> 4, tx = tid & 15;
  int myc = tid & 63;
  float acc[4][4] = {};
  float cs = 0.f;
  for (int rb=r0; rb<r1; rb+=16){
    if (tid < 16){
      int row = rb + tid;
      float f0=0,f1=0,f2=0,f3=0,f4=0,f5=0;
      if (row < r1){
        int bn = row / Kk;
        int b = bn >> 12, n = bn & 4095;
        int j = idx[row];
        const float* xb = x + b*3*Nn;
        f0=xb[j]; f1=xb[Nn+j]; f2=xb[2*Nn+j];
        f3=xb[n]; f4=xb[Nn+n]; f5=xb[2*Nn+n];
      }
      fsh[tid][0]=f0; fsh[tid][1]=f1; fsh[tid][2]=f2;
      fsh[tid][3]=f3; fsh[tid][4]=f4; fsh[tid][5]=f5;
    }
    __syncthreads();
    #pragma unroll
    for (int k=0;k<4;++k){
      int rr = (tid>>6) + k*4;
      float y = 0.f;
      #pragma unroll
      for (int i=0;i<6;++i) y = fmaf(fsh[rr][i], W1s[i][myc], y);
      float v = fmaxf(fmaf(y, scs[myc], shs[myc]), 0.f);
      if (rb + rr >= r1) v = 0.f;
      Aw[rr][myc] = v;
      cs += v;
    }
    __syncthreads();
    for (int r=0;r<16;++r){
      float4 af = *(const float4*)&Aw[r][ty*4];
      float4 bf = *(const float4*)&Aw[r][tx*4];
      float a[4] = {af.x, af.y, af.z, af.w};
      float bq[4] = {bf.x, bf.y, bf.z, bf.w};
      #pragma unroll
      for (int u=0;u<4;++u)
        #pragma unroll
        for (int v=0;v<4;++v) acc[u][v]=fmaf(a[u],bq[v],acc[u][v]);
    }
    __syncthreads();
  }
  #pragma unroll
  for (int u=0;u<4;++u)
    #pragma unroll
    for (int v=0;v<4;++v)
      atomicAdd(&G2[(size_t)(ty*4+u)*64 + tx*4+v], acc[u][v]);
  atomicAdd(&sum2[myc], cs);
}

// ---------------- fused layers 1+2: gather->H1->x1, H1@W2 -> H2(bf16) + x2 ----------------
__global__ __launch_bounds__(64) void fl12_kernel(const float* __restrict__ x,
    const int* __restrict__ idx, const float* __restrict__ W1f,
    const float* __restrict__ sc1v, const float* __restrict__ sh1v,
    const float* __restrict__ W2f, const float* __restrict__ sc2v,
    const float* __restrict__ sh2v, bf16* __restrict__ H2, bf16* __restrict__ cat){
  __shared__ float fsh[Kk][6];
  __shared__ float h1[Kk][64];
  __shared__ float mm[4][64];
  int bn = blockIdx.x, b = bn>>12, n = bn & 4095;
  int tid = threadIdx.x;
  if (tid < Kk){
    int j = idx[(size_t)bn*Kk + tid];
    const float* xb = x + b*3*Nn;
    fsh[tid][0]=xb[j]; fsh[tid][1]=xb[Nn+j]; fsh[tid][2]=xb[2*Nn+j];
    fsh[tid][3]=xb[n]; fsh[tid][4]=xb[Nn+n]; fsh[tid][5]=xb[2*Nn+n];
  }
  __syncthreads();
  {
    float sc=sc1v[tid], sh=sh1v[tid];
    float w[6];
    #pragma unroll
    for (int i=0;i<6;++i) w[i]=W1f[i*64+tid];
    float mx = 0.f;
    #pragma unroll
    for (int r=0;r<Kk;++r){
      float y=0.f;
      #pragma unroll
      for (int i=0;i<6;++i) y = fmaf(fsh[r][i], w[i], y);
      float v = fmaxf(fmaf(y,sc,sh),0.f);
      h1[r][tid]=v;
      mx = fmaxf(mx,v);
    }
    cat[(size_t)bn*512 + tid] = f2b(mx);
  }
  __syncthreads();
  int q = tid >> 4, c0 = (tid & 15)*4;
  float acc[5][4]={};
  for (int i0=0;i0<64;i0+=4){
    float hv[5][4];
    #pragma unroll
    for (int l=0;l<5;++l){
      float4 t4 = *(const float4*)&h1[q*5+l][i0];
      hv[l][0]=t4.x; hv[l][1]=t4.y; hv[l][2]=t4.z; hv[l][3]=t4.w;
    }
    #pragma unroll
    for (int ii=0;ii<4;++ii){
      const float* wp = W2f + (i0+ii)*64 + c0;
      float w0=wp[0],w1=wp[1],w2=wp[2],w3=wp[3];
      #pragma unroll
      for (int l=0;l<5;++l){
        float hvv=hv[l][ii];
        acc[l][0]=fmaf(hvv,w0,acc[l][0]);
        acc[l][1]=fmaf(hvv,w1,acc[l][1]);
        acc[l][2]=fmaf(hvv,w2,acc[l][2]);
        acc[l][3]=fmaf(hvv,w3,acc[l][3]);
      }
    }
  }
  float sc[4],sh[4];
  #pragma unroll
  for (int cb=0;cb<4;++cb){ sc[cb]=sc2v[c0+cb]; sh[cb]=sh2v[c0+cb]; }
  float mx[4]={0,0,0,0};
  #pragma unroll
  for (int l=0;l<5;++l){
    unsigned short us[4];
    #pragma unroll
    for (int cb=0;cb<4;++cb){
      float v=fmaxf(fmaf(acc[l][cb],sc[cb],sh[cb]),0.f);
      mx[cb]=fmaxf(mx[cb],v);
      us[cb]=f2bu(v);
    }
    uint2 v2; v2.x = us[0]|((unsigned)us[1]<<16); v2.y=us[2]|((unsigned)us[3]<<16);
    *(uint2*)(H2 + ((size_t)bn*Kk + q*5+l)*64 + c0) = v2;
  }
  #pragma unroll
  for (int cb=0;cb<4;++cb) mm[q][c0+cb]=mx[cb];
  __syncthreads();
  {
    float M0 = fmaxf(fmaxf(mm[0][tid],mm[1][tid]),fmaxf(mm[2][tid],mm[3][tid]));
    cat[(size_t)bn*512 + 64 + tid] = f2b(M0);
  }
}

// ---------------- layer-4 stats: fp32 produce (bit-identical chain) + MFMA Gram ----------------
// 64-row chunks; H3 written transposed bf16; Gram accumulated in MFMA VGPRs across chunks.
__global__ __launch_bounds__(512) void stats4_kernel(const bf16* __restrict__ H2,
    const float* __restrict__ W3f, const float* __restrict__ sc3v, const float* __restrict__ sh3v,
    float* __restrict__ G4, float* __restrict__ sum4){
  __shared__ float W3s[64*128];     // swizzled granules (32 KB)
  __shared__ float h2s[64][64];     // 16 KB
  __shared__ short H3T[128*68];     // transposed bf16 H3 chunk (17 KB), stride 68
  int tid = threadIdx.x, lane = tid & 63, w = tid >> 6;   // 8 waves
  for (int u=tid; u<8192; u+=512){
    int i = u>>7, c = u&127;
    W3s[i*128 + sw4(c>>2)*4 + (c&3)] = W3f[u];
  }
  int rg = tid>>5, cg = tid&31;     // produce: rows rg*4..+3, cols cg*4..+3
  float sca[4], sha[4];
  #pragma unroll
  for (int k=0;k<4;++k){ sca[k]=sc3v[cg*4+k]; sha[k]=sh3v[cg*4+k]; }
  int mt = w>>1, nt0 = (w&1)*2, nt1 = nt0+1;  // gram: wave -> 2 of 16 32x32 tiles
  int arow = (mt*32 + (lane&31))*68;
  int brow0 = (nt0*32 + (lane&31))*68;
  int brow1 = (nt1*32 + (lane&31))*68;
  int ko = (lane>>5)*8;
  floatx16 acc0, acc1;
  #pragma unroll
  for (int q=0;q<16;++q){ acc0[q]=0.f; acc1[q]=0.f; }
  float cs[4] = {0.f,0.f,0.f,0.f};
  int rpc = Mrows / gridDim.x;       // 512 blocks -> 1280 (20 chunks of 64)
  int r0 = blockIdx.x * rpc;
  for (int rb=r0; rb<r0+rpc; rb+=64){
    // stage h2s: 64x64 bf16 -> fp32
    {
      int row = tid>>3, c0 = (tid&7)*8;
      U4b v; v.q = *(const uint4*)&H2[(size_t)(rb+row)*64 + c0];
      float f[8];
      #pragma unroll
      for (int j=0;j<8;++j) f[j] = bits2f(v.s[j]);
      *(float4*)&h2s[row][c0]   = make_float4(f[0],f[1],f[2],f[3]);
      *(float4*)&h2s[row][c0+4] = make_float4(f[4],f[5],f[6],f[7]);
    }
    __syncthreads();
    // produce: 4 rows x 4 cols, i-ascending fmaf chain (bit-identical to fl34 stage 1)
    {
      float y[4][4];
      #pragma unroll
      for (int r=0;r<4;++r)
        #pragma unroll
        for (int k=0;k<4;++k) y[r][k]=0.f;
      for (int i=0;i<64;++i){
        float4 wv = *(const float4*)&W3s[i*128 + sw4(cg)*4];
        float h0=h2s[rg*4+0][i], h1=h2s[rg*4+1][i], h2v=h2s[rg*4+2][i], h3=h2s[rg*4+3][i];
        y[0][0]=fmaf(h0,wv.x,y[0][0]); y[0][1]=fmaf(h0,wv.y,y[0][1]);
        y[0][2]=fmaf(h0,wv.z,y[0][2]); y[0][3]=fmaf(h0,wv.w,y[0][3]);
        y[1][0]=fmaf(h1,wv.x,y[1][0]); y[1][1]=fmaf(h1,wv.y,y[1][1]);
        y[1][2]=fmaf(h1,wv.z,y[1][2]); y[1][3]=fmaf(h1,wv.w,y[1][3]);
        y[2][0]=fmaf(h2v,wv.x,y[2][0]); y[2][1]=fmaf(h2v,wv.y,y[2][1]);
        y[2][2]=fmaf(h2v,wv.z,y[2][2]); y[2][3]=fmaf(h2v,wv.w,y[2][3]);
        y[3][0]=fmaf(h3,wv.x,y[3][0]); y[3][1]=fmaf(h3,wv.y,y[3][1]);
        y[3][2]=fmaf(h3,wv.z,y[3][2]); y[3][3]=fmaf(h3,wv.w,y[3][3]);
      }
      #pragma unroll
      for (int k=0;k<4;++k){
        unsigned short p[4];
        #pragma unroll
        for (int r=0;r<4;++r){
          float va = fmaxf(fmaf(y[r][k], sca[k], sha[k]), 0.f);
          cs[k] += va;
          p[r] = f2bu(va);
        }
        uint2 pk; pk.x = p[0] | ((unsigned)p[1]<<16); pk.y = p[2] | ((unsigned)p[3]<<16);
        *(uint2*)&H3T[(cg*4+k)*68 + rg*4] = pk;   // transposed bf16 (variance path only)
      }
    }
    __syncthreads();
    // Gram via MFMA: 4 K-steps of 16 over the 64-row chunk
    #pragma unroll
    for (int kc=0;kc<64;kc+=16){
      Frag a, b0, b1;
      const short* ap  = &H3T[arow  + kc + ko];
      const short* bp0 = &H3T[brow0 + kc + ko];
      const short* bp1 = &H3T[brow1 + kc + ko];
      a.u2[0]  = *(const uint2*)ap;   a.u2[1]  = *(const uint2*)(ap+4);
      b0.u2[0] = *(const uint2*)bp0;  b0.u2[1] = *(const uint2*)(bp0+4);
      b1.u2[0] = *(const uint2*)bp1;  b1.u2[1] = *(const uint2*)(bp1+4);
      acc0 = __builtin_amdgcn_mfma_f32_32x32x16_bf16(a.v, b0.v, acc0, 0, 0, 0);
      acc1 = __builtin_amdgcn_mfma_f32_32x32x16_bf16(a.v, b1.v, acc1, 0, 0, 0);
    }
    __syncthreads();
  }
  int col = lane & 31, rbase = 4*(lane>>5);
  #pragma unroll
  for (int r=0;r<16;++r){
    int row = (r&3) + 8*(r>>2) + rbase;
    atomicAdd(&G4[(size_t)(mt*32+row)*128 + nt0*32+col], acc0[r]);
    atomicAdd(&G4[(size_t)(mt*32+row)*128 + nt1*32+col], acc1[r]);
  }
  #pragma unroll
  for (int k=0;k<4;++k) atomicAdd(&sum4[cg*4+k], cs[k]);
}

// ---------------- fused layers 3+4: 4 points/block. H2->H3->x3, H3@W4->x4 ----------------
__global__ __launch_bounds__(512,2) void fl34_kernel(const bf16* __restrict__ H2,
    const float* __restrict__ W3f, const float* __restrict__ sc3v, const float* __restrict__ sh3v,
    const float* __restrict__ W4f, const float* __restrict__ sc4v, const float* __restrict__ sh4v,
    bf16* __restrict__ cat){
  __shared__ float h2s[4][Kk][64];      // 20 KB
  __shared__ float h3s[4][Kk][128];     // 40 KB
  __shared__ float w4s[16][256];        // 16 KB, aliased as mm[4][4][256] after K-loop
  int tid = threadIdx.x;
  int bn0 = blockIdx.x*4;
  int pt = tid >> 7, tid2 = tid & 127;
  for (int u=tid; u<4*Kk*64; u+=512){
    int p = u / 1280, rem = u - p*1280;
    h2s[p][rem>>6][rem&63] = b2f(H2[((size_t)(bn0+p)*Kk + (rem>>6))*64 + (rem&63)]);
  }
  __syncthreads();
  {
    int c = tid2;
    float y[Kk];
    #pragma unroll
    for (int r=0;r<Kk;++r) y[r]=0.f;
    for (int i=0;i<64;++i){
      float w = W3f[i*128 + c];
      #pragma unroll
      for (int r=0;r<Kk;++r) y[r]=fmaf(h2s[pt][r][i], w, y[r]);
    }
    float sc=sc3v[c], sh=sh3v[c];
    float mx=0.f;
    #pragma unroll
    for (int r=0;r<Kk;++r){
      float v=fmaxf(fmaf(y[r],sc,sh),0.f);
      h3s[pt][r][c]=v;
      mx=fmaxf(mx,v);
    }
    cat[(size_t)(bn0+pt)*512 + 128 + c] = f2b(mx);
  }
  __syncthreads();
  int q = tid2 >> 5, cbase = tid2 & 31;
  float acc[5][8]={};
  for (int i0=0;i0<128;i0+=16){
    for (int u=tid;u<4096;u+=512) w4s[u>>8][u&255]=W4f[(size_t)(i0+(u>>8))*256+(u&255)];
    __syncthreads();
    for (int ii=0;ii<16;++ii){
      float w[8];
      #pragma unroll
      for (int cb=0;cb<8;++cb) w[cb]=w4s[ii][cbase + cb*32];
      float hv[5];
      #pragma unroll
      for (int l=0;l<5;++l) hv[l]=h3s[pt][q*5+l][i0+ii];
      #pragma unroll
      for (int l=0;l<5;++l)
        #pragma unroll
        for (int cb=0;cb<8;++cb) acc[l][cb]=fmaf(hv[l],w[cb],acc[l][cb]);
    }
    __syncthreads();
  }
  float sc[8],sh[8];
  #pragma unroll
  for (int cb=0;cb<8;++cb){ sc[cb]=sc4v[cbase+cb*32]; sh[cb]=sh4v[cbase+cb*32]; }
  float mx[8];
  #pragma unroll
  for (int cb=0;cb<8;++cb) mx[cb]=0.f;
  #pragma unroll
  for (int l=0;l<5;++l)
    #pragma unroll
    for (int cb=0;cb<8;++cb){
      float v=fmaxf(fmaf(acc[l][cb],sc[cb],sh[cb]),0.f);
      mx[cb]=fmaxf(mx[cb],v);
    }
  float* mmf = &w4s[0][0];
  #pragma unroll
  for (int cb=0;cb<8;++cb) mmf[((pt*4+q)<<8) + cbase + cb*32] = mx[cb];
  __syncthreads();
  for (int u=tid; u<1024; u+=512){
    int p = u >> 8, c = u & 255;
    float M0 = fmaxf(fmaxf(mmf[((p*4+0)<<8)+c], mmf[((p*4+1)<<8)+c]),
                     fmaxf(mmf[((p*4+2)<<8)+c], mmf[((p*4+3)<<8)+c]));
    cat[(size_t)(bn0+p)*512 + 256 + c] = f2b(M0);
  }
}

// ---------------- layer 5: cat(bf16,512) @ W5, BN+ReLU, fp32 transposed store ----------------
__global__ __launch_bounds__(256) void l5_kernel(const bf16* __restrict__ cat,
                                                const float* __restrict__ Wf,
                                                const float* __restrict__ scale,
                                                const float* __restrict__ shift,
                                                float* __restrict__ out){
  __shared__ float cr[8][512];
  __shared__ float ob[8][512];
  int tid = threadIdx.x;
  int bn0 = blockIdx.x*8;
  for (int u=tid; u<8*512; u+=256) cr[u>>9][u&511] = b2f(cat[(size_t)bn0*512 + u]);
  __syncthreads();
  int rp = tid >> 6, cg = tid & 63, c0 = cg*8;
  int ra = rp*2, rb = rp*2+1;
  float acc[2][8] = {};
  for (int i=0;i<512;++i){
    float h0 = cr[ra][i], h1 = cr[rb][i];
    const float* wp = Wf + (size_t)i*512 + c0;
    float4 wa = *(const float4*)wp;
    float4 wb = *(const float4*)(wp+4);
    float w[8] = {wa.x,wa.y,wa.z,wa.w,wb.x,wb.y,wb.z,wb.w};
    #pragma unroll
    for (int k=0;k<8;++k){
      acc[0][k] = fmaf(h0, w[k], acc[0][k]);
      acc[1][k] = fmaf(h1, w[k], acc[1][k]);
    }
  }
  float sc[8], sh[8];
  #pragma unroll
  for (int k=0;k<8;++k){ sc[k]=scale[c0+k]; sh[k]=shift[c0+k]; }
  #pragma unroll
  for (int k=0;k<8;++k){
    ob[ra][c0+k] = fmaxf(fmaf(acc[0][k], sc[k], sh[k]), 0.f);
    ob[rb][c0+k] = fmaxf(fmaf(acc[1][k], sc[k], sh[k]), 0.f);
  }
  __syncthreads();
  int b = bn0 >> 12, n0 = bn0 & 4095;
  for (int u=tid; u<512; u+=256){
    float4 v0 = make_float4(ob[0][u], ob[1][u], ob[2][u], ob[3][u]);
    float4 v1 = make_float4(ob[4][u], ob[5][u], ob[6][u], ob[7][u]);
    float* op = out + ((size_t)b*512 + u)*4096 + n0;
    *(float4*)(op)   = v0;
    *(float4*)(op+4) = v1;
  }
}

extern "C" void kernel_launch(void* const* d_in, const int* in_sizes, int n_in,
                              void* d_out, int out_size, void* d_ws, size_t ws_size,
                              hipStream_t stream){
  const float* x   = (const float*)d_in[0];
  const float* W1f = (const float*)d_in[1];
  const float* W2f = (const float*)d_in[2];
  const float* W3f = (const float*)d_in[3];
  const float* W4f = (const float*)d_in[4];
  const float* W5f = (const float*)d_in[5];
  const float* g1=(const float*)d_in[6],  *b1=(const float*)d_in[7];
  const float* g2=(const float*)d_in[8],  *b2=(const float*)d_in[9];
  const float* g3=(const float*)d_in[10], *b3=(const float*)d_in[11];
  const float* g4=(const float*)d_in[12], *b4=(const float*)d_in[13];
  const float* g5=(const float*)d_in[14], *b5=(const float*)d_in[15];
  float* out = (float*)d_out;

  char* w = (char*)d_ws;
  size_t off = 0;
  auto alloc = [&](size_t bytes)->void*{
    void* p = w + off;
    off = (off + bytes + 255) & ~(size_t)255;
    return p;
  };

  int*  idxb = (int*) alloc((size_t)BN*Kk*4);          // 2.6 MB
  bf16* H2   = (bf16*)alloc((size_t)Mrows*64*2);       // 84 MB
  bf16* catb = (bf16*)alloc((size_t)BN*512*2);         // 33.6 MB
  float* pv  = (float*)H2;                             // KNN scratch aliases H2
  int*   pib = (int*)((char*)H2 + (size_t)BN*4*Kk*4);

  size_t statsStart = off;
  float* partf=(float*)alloc(256*48*4);
  float* Gf=(float*)alloc(36*4);
  float* sumf=(float*)alloc(8*4);
  float* G2=(float*)alloc(4096*4);   float* sum2=(float*)alloc(64*4);
  float* G3=(float*)alloc(4096*4);   float* sum3=(float*)alloc(64*4);
  float* G4=(float*)alloc(16384*4);  float* sum4=(float*)alloc(128*4);
  float* G5=(float*)alloc(262144*4); float* sum5=(float*)alloc(512*4);
  float* P1=(float*)alloc(384*4);
  float* P2=(float*)alloc(4096*4);
  float* P3=(float*)alloc(8192*4);
  float* P4=(float*)alloc(32768*4);
  float* P5=(float*)alloc(262144*4);
  float* sc1=(float*)alloc(64*4);   float* sh1=(float*)alloc(64*4);
  float* sc2=(float*)alloc(64*4);   float* sh2=(float*)alloc(64*4);
  float* sc3=(float*)alloc(128*4);  float* sh3=(float*)alloc(128*4);
  float* sc4=(float*)alloc(256*4);  float* sh4=(float*)alloc(256*4);
  float* sc5=(float*)alloc(512*4);  float* sh5=(float*)alloc(512*4);
  size_t statsEnd = off;

  int statsFloats = (int)((statsEnd - statsStart)/4);
  zero_kernel<<<(statsFloats+255)/256,256,0,stream>>>((float*)(w+statsStart), statsFloats);

  knnA_kernel<<<512,256,0,stream>>>(x, pv, pib);
  knnB_kernel<<<BN/256,256,0,stream>>>(pv, pib, idxb);

  const float invM  = 1.0f/(float)Mrows;
  const float invM5 = 1.0f/(float)BN;

  // layer 1 stats
  gramf_kernel<<<256,256,0,stream>>>(x, idxb, partf);
  reducef_kernel<<<1,64,0,stream>>>(partf, Gf, sumf);
  kP_kernel<<<2,256,0,stream>>>(Gf, W1f, P1, 6, 64);
  kFinal_kernel<<<1,256,0,stream>>>(P1, sumf, W1f, g1, b1, sc1, sh1, 6, 64, invM);

  // layer 2 stats (on-the-fly H1)
  stats2_kernel<<<2048,256,0,stream>>>(x, idxb, W1f, sc1, sh1, G2, sum2);
  kP_kernel<<<16,256,0,stream>>>(G2, W2f, P2, 64, 64);
  kFinal_kernel<<<1,256,0,stream>>>(P2, sum2, W2f, g2, b2, sc2, sh2, 64, 64, invM);

  // apply layers 1+2
  fl12_kernel<<<BN,64,0,stream>>>(x, idxb, W1f, sc1, sh1, W2f, sc2, sh2, H2, catb);

  // layer 3 stats from H2 (MFMA gram, bit-exact products on bf16 H2)
  colsum_kernel<64,bf16><<<512,256,0,stream>>>(H2, Mrows, sum3);
  gramM_kernel<64><<<512,256,0,stream>>>(H2, Mrows, G3);
  kP_kernel<<<32,256,0,stream>>>(G3, W3f, P3, 64, 128);
  kFinal_kernel<<<1,256,0,stream>>>(P3, sum3, W3f, g3, b3, sc3, sh3, 64, 128, invM);

  // layer 4 stats (fp32 produce + MFMA gram)
  stats4_kernel<<<512,512,0,stream>>>(H2, W3f, sc3, sh3, G4, sum4);
  kP_kernel<<<128,256,0,stream>>>(G4, W4f, P4, 128, 256);
  kFinal_kernel<<<1,256,0,stream>>>(P4, sum4, W4f, g4, b4, sc4, sh4, 128, 256, invM);

  // apply layers 3+4 (4 points per block)
  fl34_kernel<<<BN/4,512,0,stream>>>(H2, W3f, sc3, sh3, W4f, sc4, sh4, catb);

  // layer 5 (MFMA gram on bf16 cat)
  colsum_kernel<512,bf16><<<512,256,0,stream>>>(catb, BN, sum5);
  gramM_kernel<512><<<512,256,0,stream>>>(catb, BN, G5);
  kP_kernel<<<1024,256,0,stream>>>(G5, W5f, P5, 512, 512);
  kFinal_kernel<<<2,256,0,stream>>>(P5, sum5, W5f, g5, b5, sc5, sh5, 512, 512, invM5);
  l5_kernel<<<BN/8,256,0,stream>>>(catb, W5f, sc5, sh5, out);
}

// Round 8
// 3738.709 us; speedup vs baseline: 1.6276x; 1.1679x over previous
//
#include <hip/hip_runtime.h>
#include <hip/hip_bf16.h>
#include <cfloat>

using bf16 = __hip_bfloat16;

typedef short short8 __attribute__((ext_vector_type(8)));
typedef float floatx16 __attribute__((ext_vector_type(16)));
union Frag { short8 v; uint2 u2[2]; };
union U4b { uint4 q; unsigned short s[8]; };

constexpr int Bb = 8, Nn = 4096, Kk = 20;
constexpr int BN = Bb * Nn;                     // 32768
constexpr int Mrows = BN * Kk;                  // 655360
constexpr float EPSf = 1e-5f;

static __device__ __forceinline__ float b2f(bf16 v){ return __bfloat162float(v); }
static __device__ __forceinline__ bf16 f2b(float v){ return __float2bfloat16(v); }
static __device__ __forceinline__ unsigned short f2bu(float v){
  union { bf16 b; unsigned short u; } cv; cv.b = __float2bfloat16(v); return cv.u;
}
static __device__ __forceinline__ float bits2f(unsigned short u){
  union { unsigned int i; float f; } c; c.i = ((unsigned)u)<<16; return c.f;
}
static __device__ __forceinline__ float ldf(bf16 v){ return b2f(v); }
static __device__ __forceinline__ float ldf(float v){ return v; }
// granule XOR swizzles (float4 granules): conflict-free strided b128 access
static __device__ __forceinline__ int sw4(int g){ return g ^ (g >> 3); }   // 32 granules
static __device__ __forceinline__ int sw6(int g){ return g ^ (g >> 3); }   // 64 granules

// ---------------- zero workspace region ----------------
__global__ void zero_kernel(float* __restrict__ p, int n){
  int i = blockIdx.x*256 + threadIdx.x;
  if (i < n) p[i] = 0.f;
}

// ---------------- KNN phase A ----------------
__global__ __launch_bounds__(256) void knnA_kernel(const float* __restrict__ x,
                                                   float* __restrict__ pv, int* __restrict__ pi){
#pragma clang fp contract(off)
  __shared__ float4 p4[1024];
  int blk = blockIdx.x;
  int stripe = blk & 3;
  int chunk  = (blk >> 2) & 15;
  int b      = blk >> 6;
  const float* xb = x + b*3*Nn;
  int j0 = stripe*1024;
  for (int u = threadIdx.x; u < 1024; u += 256){
    int j = j0 + u;
    float a0 = xb[j];
    float a1 = xb[Nn + j];
    float a2 = xb[2*Nn + j];
    float s = a0*a0; s = s + a1*a1; s = s + a2*a2;
    p4[u] = make_float4(a0, a1, a2, s);
  }
  __syncthreads();
  int i = chunk*256 + threadIdx.x;
  float xi = xb[i], yi = xb[Nn+i], zi = xb[2*Nn+i];
  float ni = xi*xi; ni = ni + yi*yi; ni = ni + zi*zi;
  float mni = -ni;
  float tv[Kk]; int ti[Kk];
  #pragma unroll
  for (int s=0;s<Kk;++s){ tv[s] = -FLT_MAX; ti[s] = 0; }
  for (int u=0; u<1024; ++u){
    float4 p = p4[u];
    float dot = xi*p.x; dot = dot + yi*p.y; dot = dot + zi*p.z;
    float inner = -2.0f*dot;
    float nd = mni - inner; nd = nd - p.w;
    if (nd > tv[Kk-1]){
      #pragma unroll
      for (int s=Kk-1; s>=1; --s){
        bool cs = nd > tv[s];
        bool cp = nd > tv[s-1];
        tv[s] = cs ? (cp ? tv[s-1] : nd) : tv[s];
        ti[s] = cs ? (cp ? ti[s-1] : (j0+u)) : ti[s];
      }
      if (nd > tv[0]){ tv[0] = nd; ti[0] = j0+u; }
    }
  }
  long long base = ((long long)(b*Nn + i)*4 + stripe)*Kk;
  #pragma unroll
  for (int s=0;s<Kk;++s){ pv[base+s] = tv[s]; pi[base+s] = ti[s]; }
}

// ---------------- KNN phase B ----------------
__global__ __launch_bounds__(256) void knnB_kernel(const float* __restrict__ pv,
                                                   const int* __restrict__ pi,
                                                   int* __restrict__ idx){
  int p = blockIdx.x*256 + threadIdx.x;
  if (p >= BN) return;
  long long base = (long long)p*4*Kk;
  float av[Kk]; int ai[Kk];
  #pragma unroll
  for (int s=0;s<Kk;++s){ av[s]=pv[base+s]; ai[s]=pi[base+s]; }
  for (int t=Kk; t<4*Kk; ++t){
    float nd = pv[base+t]; int j = pi[base+t];
    if (nd > av[Kk-1]){
      #pragma unroll
      for (int s=Kk-1;s>=1;--s){
        bool cs = nd > av[s];
        bool cp = nd > av[s-1];
        av[s] = cs ? (cp?av[s-1]:nd) : av[s];
        ai[s] = cs ? (cp?ai[s-1]:j) : ai[s];
      }
      if (nd > av[0]){ av[0]=nd; ai[0]=j; }
    }
  }
  #pragma unroll
  for (int s=0;s<Kk;++s) idx[(long long)p*Kk+s] = ai[s];
}

// ---------------- layer-1 feature stats ----------------
__global__ __launch_bounds__(256) void gramf_kernel(const float* __restrict__ x,
                                                    const int* __restrict__ idx,
                                                    float* __restrict__ part){
  float acc[36]; float s6[6];
  #pragma unroll
  for (int a=0;a<36;++a) acc[a]=0.f;
  #pragma unroll
  for (int a=0;a<6;++a) s6[a]=0.f;
  for (long long row = blockIdx.x*256 + threadIdx.x; row < Mrows; row += (long long)gridDim.x*256){
    int bn = (int)(row / Kk);
    int b = bn >> 12, n = bn & 4095;
    int j = idx[row];
    const float* xb = x + b*3*Nn;
    float f[6];
    f[0]=xb[j];  f[1]=xb[Nn+j];  f[2]=xb[2*Nn+j];
    f[3]=xb[n];  f[4]=xb[Nn+n];  f[5]=xb[2*Nn+n];
    #pragma unroll
    for (int a=0;a<6;++a){
      s6[a] += f[a];
      #pragma unroll
      for (int c=0;c<6;++c) acc[a*6+c] = fmaf(f[a], f[c], acc[a*6+c]);
    }
  }
  __shared__ float red[256];
  for (int v=0; v<42; ++v){
    red[threadIdx.x] = (v<36)? acc[v] : s6[v-36];
    __syncthreads();
    for (int s=128; s>0; s>>=1){
      if (threadIdx.x < s) red[threadIdx.x] += red[threadIdx.x+s];
      __syncthreads();
    }
    if (threadIdx.x==0) part[blockIdx.x*48 + v] = red[0];
    __syncthreads();
  }
}

__global__ void reducef_kernel(const float* __restrict__ part, float* __restrict__ Gf,
                               float* __restrict__ sumf){
  int t = threadIdx.x;
  if (t < 42){
    float s = 0.f;
    for (int i=0;i<256;++i) s += part[i*48 + t];
    if (t<36) Gf[t]=s; else sumf[t-36]=s;
  }
}

// ---------------- MFMA Gram: G = H^T H over bf16 H ----------------
template<int CIN>
__global__ __launch_bounds__(256) void gramM_kernel(const bf16* __restrict__ H, int M,
                                                    float* __restrict__ G){
  constexpr int Tt = CIN/64;
  int tile = blockIdx.x % (Tt*Tt);
  int chunk = blockIdx.x / (Tt*Tt);
  int nchunks = gridDim.x / (Tt*Tt);
  int tr = tile / Tt, tc = tile % Tt;
  bool diag = (tr == tc);
  __shared__ short HTa[64*68];
  __shared__ short HTb[64*68];
  int rpc = M / nchunks;
  int r0 = chunk*rpc;
  int tid = threadIdx.x, lane = tid & 63, w = tid >> 6;
  int mt = w >> 1, nt = w & 1;
  floatx16 acc;
  #pragma unroll
  for (int q=0;q<16;++q) acc[q]=0.f;
  const short* Bbase = diag ? HTa : HTb;
  int arow = (mt*32 + (lane&31))*68;
  int brow = (nt*32 + (lane&31))*68;
  int ko = (lane>>5)*8;
  for (int rb=r0; rb<r0+rpc; rb+=64){
    #pragma unroll
    for (int s=0;s<2;++s){
      int e = tid + s*256;
      int row = e >> 3, c0 = (e & 7)*8;
      U4b va; va.q = *(const uint4*)&H[(size_t)(rb+row)*CIN + tr*64 + c0];
      #pragma unroll
      for (int j=0;j<8;++j) HTa[(c0+j)*68 + row] = (short)va.s[j];
      if (!diag){
        U4b vb; vb.q = *(const uint4*)&H[(size_t)(rb+row)*CIN + tc*64 + c0];
        #pragma unroll
        for (int j=0;j<8;++j) HTb[(c0+j)*68 + row] = (short)vb.s[j];
      }
    }
    __syncthreads();
    #pragma unroll
    for (int kc=0;kc<64;kc+=16){
      Frag a, b;
      const short* ap = &HTa[arow + kc + ko];
      const short* bp = &Bbase[brow + kc + ko];
      a.u2[0] = *(const uint2*)ap;  a.u2[1] = *(const uint2*)(ap+4);
      b.u2[0] = *(const uint2*)bp;  b.u2[1] = *(const uint2*)(bp+4);
      acc = __builtin_amdgcn_mfma_f32_32x32x16_bf16(a.v, b.v, acc, 0, 0, 0);
    }
    __syncthreads();
  }
  int col = lane & 31, rbase = 4*(lane>>5);
  #pragma unroll
  for (int r=0;r<16;++r){
    int row = (r&3) + 8*(r>>2) + rbase;
    atomicAdd(&G[(size_t)(tr*64 + mt*32 + row)*CIN + tc*64 + nt*32 + col], acc[r]);
  }
}

// ---------------- column sums of H ----------------
template<int CIN, typename T>
__global__ __launch_bounds__(256) void colsum_kernel(const T* __restrict__ H, int M,
                                                     float* __restrict__ sumh){
  int rpb = (M + gridDim.x - 1)/gridDim.x;
  int r0 = blockIdx.x*rpb, r1 = min(M, r0+rpb);
  if constexpr (CIN <= 256){
    constexpr int RP = 256/CIN;
    int c = threadIdx.x % CIN;
    int sub = threadIdx.x / CIN;
    float a = 0.f;
    for (int r=r0+sub; r<r1; r+=RP) a += ldf(H[(size_t)r*CIN + c]);
    atomicAdd(&sumh[c], a);
  } else {
    float a0=0.f, a1=0.f;
    for (int r=r0;r<r1;++r){
      a0 += ldf(H[(size_t)r*CIN + threadIdx.x]);
      a1 += ldf(H[(size_t)r*CIN + threadIdx.x + 256]);
    }
    atomicAdd(&sumh[threadIdx.x], a0);
    atomicAdd(&sumh[threadIdx.x+256], a1);
  }
}

// ---------------- P = G @ W ----------------
__global__ void kP_kernel(const float* __restrict__ G, const float* __restrict__ Wf,
                          float* __restrict__ P, int Cin, int Cout){
  int id = blockIdx.x*256 + threadIdx.x;
  if (id >= Cin*Cout) return;
  int i = id / Cout, j = id - i*Cout;
  float s = 0.f;
  for (int k=0;k<Cin;++k) s = fmaf(G[(size_t)i*Cin+k], Wf[(size_t)k*Cout+j], s);
  P[id] = s;
}

// ---------------- scale/shift from Gram-derived BN stats ----------------
__global__ void kFinal_kernel(const float* __restrict__ P, const float* __restrict__ sumh,
                              const float* __restrict__ Wf, const float* __restrict__ g,
                              const float* __restrict__ bb, float* __restrict__ scale,
                              float* __restrict__ shift, int Cin, int Cout, float invM){
  int j = blockIdx.x*256 + threadIdx.x;
  if (j >= Cout) return;
  float mean=0.f, e2=0.f;
  for (int i=0;i<Cin;++i){
    float w = Wf[(size_t)i*Cout + j];
    mean = fmaf(sumh[i], w, mean);
    e2   = fmaf(w, P[(size_t)i*Cout + j], e2);
  }
  mean *= invM; e2 *= invM;
  float var = e2 - mean*mean;
  float inv = rsqrtf(var + EPSf);
  float sc = g[j]*inv;
  scale[j]=sc;
  shift[j]=bb[j] - mean*sc;
}

// ---------------- layer-2 stats: fp32 H1 produce + bf16 MFMA Gram + fused colsum ----------------
__global__ __launch_bounds__(512) void stats2_kernel(const float* __restrict__ x,
    const int* __restrict__ idx, const float* __restrict__ W1f,
    const float* __restrict__ sc1v, const float* __restrict__ sh1v,
    float* __restrict__ G2, float* __restrict__ sum2){
  __shared__ float W1s[6][64];
  __shared__ float fsh[64][8];
  __shared__ short H1T[64*68];
  __shared__ float csum[64];
  int tid = threadIdx.x, lane = tid & 63, w = tid >> 6;   // 8 waves
  if (tid < 384) W1s[tid>>6][tid&63] = W1f[tid];
  if (tid < 64) csum[tid] = 0.f;
  // produce mapping: row-pair rp (2 rows) x 16 colgroups (4 cols)
  int rp = tid >> 4, cq = tid & 15, c0 = cq*4;
  float sca[4], sha[4];
  #pragma unroll
  for (int k=0;k<4;++k){ sca[k]=sc1v[c0+k]; sha[k]=sh1v[c0+k]; }
  // MFMA mapping: 2x2 tiles x 2 k-halves
  int mt = w & 1, nt = (w>>1) & 1, kh = w >> 2;
  int arow = (mt*32 + (lane&31))*68;
  int brow = (nt*32 + (lane&31))*68;
  int ko = (lane>>5)*8;
  floatx16 acc;
  #pragma unroll
  for (int q=0;q<16;++q) acc[q]=0.f;
  float cs[4] = {0.f,0.f,0.f,0.f};
  int rpc = Mrows / gridDim.x;
  int r0 = blockIdx.x * rpc;
  __syncthreads();
  for (int rb=r0; rb<r0+rpc; rb+=64){
    {
      int r = tid>>3, e = tid&7;
      if (e < 6){
        int grow = rb + r;
        int bn = grow / Kk;
        int b = bn >> 12, n = bn & 4095;
        int j = idx[grow];
        const float* xb = x + b*3*Nn;
        fsh[r][e] = (e<3) ? xb[e*Nn + j] : xb[(e-3)*Nn + n];
      }
    }
    __syncthreads();
    {
      float y0[4]={0,0,0,0}, y1[4]={0,0,0,0};
      int ra = rp*2, rbw = rp*2+1;
      #pragma unroll
      for (int i=0;i<6;++i){
        float fa = fsh[ra][i], fb = fsh[rbw][i];
        float4 wv = *(const float4*)&W1s[i][c0];
        y0[0]=fmaf(fa,wv.x,y0[0]); y0[1]=fmaf(fa,wv.y,y0[1]);
        y0[2]=fmaf(fa,wv.z,y0[2]); y0[3]=fmaf(fa,wv.w,y0[3]);
        y1[0]=fmaf(fb,wv.x,y1[0]); y1[1]=fmaf(fb,wv.y,y1[1]);
        y1[2]=fmaf(fb,wv.z,y1[2]); y1[3]=fmaf(fb,wv.w,y1[3]);
      }
      #pragma unroll
      for (int k=0;k<4;++k){
        float va = fmaxf(fmaf(y0[k],sca[k],sha[k]),0.f);
        float vb = fmaxf(fmaf(y1[k],sca[k],sha[k]),0.f);
        cs[k] += va; cs[k] += vb;
        unsigned int pk = f2bu(va) | ((unsigned)f2bu(vb)<<16);
        *(unsigned int*)&H1T[(c0+k)*68 + ra] = pk;
      }
    }
    __syncthreads();
    {
      int kc = kh*32;
      #pragma unroll
      for (int s=0;s<2;++s){
        Frag a, b;
        const short* ap = &H1T[arow + kc + s*16 + ko];
        const short* bp = &H1T[brow + kc + s*16 + ko];
        a.u2[0] = *(const uint2*)ap;  a.u2[1] = *(const uint2*)(ap+4);
        b.u2[0] = *(const uint2*)bp;  b.u2[1] = *(const uint2*)(bp+4);
        acc = __builtin_amdgcn_mfma_f32_32x32x16_bf16(a.v, b.v, acc, 0, 0, 0);
      }
    }
    __syncthreads();
  }
  int col = lane & 31, rbase = 4*(lane>>5);
  #pragma unroll
  for (int r=0;r<16;++r){
    int row = (r&3) + 8*(r>>2) + rbase;
    atomicAdd(&G2[(size_t)(mt*32+row)*64 + nt*32+col], acc[r]);
  }
  #pragma unroll
  for (int k=0;k<4;++k) atomicAdd(&csum[c0+k], cs[k]);
  __syncthreads();
  if (tid < 64) atomicAdd(&sum2[tid], csum[tid]);
}

// ---------------- fused layers 1+2 ----------------
__global__ __launch_bounds__(64) void fl12_kernel(const float* __restrict__ x,
    const int* __restrict__ idx, const float* __restrict__ W1f,
    const float* __restrict__ sc1v, const float* __restrict__ sh1v,
    const float* __restrict__ W2f, const float* __restrict__ sc2v,
    const float* __restrict__ sh2v, bf16* __restrict__ H2, bf16* __restrict__ cat){
  __shared__ float fsh[Kk][6];
  __shared__ float h1[Kk][64];
  __shared__ float mm[4][64];
  int bn = blockIdx.x, b = bn>>12, n = bn & 4095;
  int tid = threadIdx.x;
  if (tid < Kk){
    int j = idx[(size_t)bn*Kk + tid];
    const float* xb = x + b*3*Nn;
    fsh[tid][0]=xb[j]; fsh[tid][1]=xb[Nn+j]; fsh[tid][2]=xb[2*Nn+j];
    fsh[tid][3]=xb[n]; fsh[tid][4]=xb[Nn+n]; fsh[tid][5]=xb[2*Nn+n];
  }
  __syncthreads();
  {
    float sc=sc1v[tid], sh=sh1v[tid];
    float w[6];
    #pragma unroll
    for (int i=0;i<6;++i) w[i]=W1f[i*64+tid];
    float mx = 0.f;
    #pragma unroll
    for (int r=0;r<Kk;++r){
      float y=0.f;
      #pragma unroll
      for (int i=0;i<6;++i) y = fmaf(fsh[r][i], w[i], y);
      float v = fmaxf(fmaf(y,sc,sh),0.f);
      h1[r][tid]=v;
      mx = fmaxf(mx,v);
    }
    cat[(size_t)bn*512 + tid] = f2b(mx);
  }
  __syncthreads();
  int q = tid >> 4, c0 = (tid & 15)*4;
  float acc[5][4]={};
  for (int i0=0;i0<64;i0+=4){
    float hv[5][4];
    #pragma unroll
    for (int l=0;l<5;++l){
      float4 t4 = *(const float4*)&h1[q*5+l][i0];
      hv[l][0]=t4.x; hv[l][1]=t4.y; hv[l][2]=t4.z; hv[l][3]=t4.w;
    }
    #pragma unroll
    for (int ii=0;ii<4;++ii){
      const float* wp = W2f + (i0+ii)*64 + c0;
      float w0=wp[0],w1=wp[1],w2=wp[2],w3=wp[3];
      #pragma unroll
      for (int l=0;l<5;++l){
        float hvv=hv[l][ii];
        acc[l][0]=fmaf(hvv,w0,acc[l][0]);
        acc[l][1]=fmaf(hvv,w1,acc[l][1]);
        acc[l][2]=fmaf(hvv,w2,acc[l][2]);
        acc[l][3]=fmaf(hvv,w3,acc[l][3]);
      }
    }
  }
  float sc[4],sh[4];
  #pragma unroll
  for (int cb=0;cb<4;++cb){ sc[cb]=sc2v[c0+cb]; sh[cb]=sh2v[c0+cb]; }
  float mx[4]={0,0,0,0};
  #pragma unroll
  for (int l=0;l<5;++l){
    unsigned short us[4];
    #pragma unroll
    for (int cb=0;cb<4;++cb){
      float v=fmaxf(fmaf(acc[l][cb],sc[cb],sh[cb]),0.f);
      mx[cb]=fmaxf(mx[cb],v);
      us[cb]=f2bu(v);
    }
    uint2 v2; v2.x = us[0]|((unsigned)us[1]<<16); v2.y=us[2]|((unsigned)us[3]<<16);
    *(uint2*)(H2 + ((size_t)bn*Kk + q*5+l)*64 + c0) = v2;
  }
  #pragma unroll
  for (int cb=0;cb<4;++cb) mm[q][c0+cb]=mx[cb];
  __syncthreads();
  {
    float M0 = fmaxf(fmaxf(mm[0][tid],mm[1][tid]),fmaxf(mm[2][tid],mm[3][tid]));
    cat[(size_t)bn*512 + 64 + tid] = f2b(M0);
  }
}

// ---------------- layer-4 stats: fp32 produce + MFMA Gram ----------------
__global__ __launch_bounds__(512) void stats4_kernel(const bf16* __restrict__ H2,
    const float* __restrict__ W3f, const float* __restrict__ sc3v, const float* __restrict__ sh3v,
    float* __restrict__ G4, float* __restrict__ sum4){
  __shared__ float W3s[64*128];
  __shared__ float h2s[64][64];
  __shared__ short H3T[128*68];
  int tid = threadIdx.x, lane = tid & 63, w = tid >> 6;
  for (int u=tid; u<8192; u+=512){
    int i = u>>7, c = u&127;
    W3s[i*128 + sw4(c>>2)*4 + (c&3)] = W3f[u];
  }
  int rg = tid>>5, cg = tid&31;
  float sca[4], sha[4];
  #pragma unroll
  for (int k=0;k<4;++k){ sca[k]=sc3v[cg*4+k]; sha[k]=sh3v[cg*4+k]; }
  int mt = w>>1, nt0 = (w&1)*2, nt1 = nt0+1;
  int arow = (mt*32 + (lane&31))*68;
  int brow0 = (nt0*32 + (lane&31))*68;
  int brow1 = (nt1*32 + (lane&31))*68;
  int ko = (lane>>5)*8;
  floatx16 acc0, acc1;
  #pragma unroll
  for (int q=0;q<16;++q){ acc0[q]=0.f; acc1[q]=0.f; }
  float cs[4] = {0.f,0.f,0.f,0.f};
  int rpc = Mrows / gridDim.x;
  int r0 = blockIdx.x * rpc;
  for (int rb=r0; rb<r0+rpc; rb+=64){
    {
      int row = tid>>3, c0 = (tid&7)*8;
      U4b v; v.q = *(const uint4*)&H2[(size_t)(rb+row)*64 + c0];
      float f[8];
      #pragma unroll
      for (int j=0;j<8;++j) f[j] = bits2f(v.s[j]);
      *(float4*)&h2s[row][c0]   = make_float4(f[0],f[1],f[2],f[3]);
      *(float4*)&h2s[row][c0+4] = make_float4(f[4],f[5],f[6],f[7]);
    }
    __syncthreads();
    // produce: 4 rows x 4 cols, i-ascending chain, float4 h-reads
    {
      float y[4][4];
      #pragma unroll
      for (int r=0;r<4;++r)
        #pragma unroll
        for (int k=0;k<4;++k) y[r][k]=0.f;
      for (int i0=0;i0<64;i0+=4){
        float4 h4[4];
        #pragma unroll
        for (int r=0;r<4;++r) h4[r] = *(const float4*)&h2s[rg*4+r][i0];
        #pragma unroll
        for (int ii=0;ii<4;++ii){
          float4 wv = *(const float4*)&W3s[(i0+ii)*128 + sw4(cg)*4];
          float h0=h4[0][ii], h1=h4[1][ii], h2v=h4[2][ii], h3=h4[3][ii];
          y[0][0]=fmaf(h0,wv.x,y[0][0]); y[0][1]=fmaf(h0,wv.y,y[0][1]);
          y[0][2]=fmaf(h0,wv.z,y[0][2]); y[0][3]=fmaf(h0,wv.w,y[0][3]);
          y[1][0]=fmaf(h1,wv.x,y[1][0]); y[1][1]=fmaf(h1,wv.y,y[1][1]);
          y[1][2]=fmaf(h1,wv.z,y[1][2]); y[1][3]=fmaf(h1,wv.w,y[1][3]);
          y[2][0]=fmaf(h2v,wv.x,y[2][0]); y[2][1]=fmaf(h2v,wv.y,y[2][1]);
          y[2][2]=fmaf(h2v,wv.z,y[2][2]); y[2][3]=fmaf(h2v,wv.w,y[2][3]);
          y[3][0]=fmaf(h3,wv.x,y[3][0]); y[3][1]=fmaf(h3,wv.y,y[3][1]);
          y[3][2]=fmaf(h3,wv.z,y[3][2]); y[3][3]=fmaf(h3,wv.w,y[3][3]);
        }
      }
      #pragma unroll
      for (int k=0;k<4;++k){
        unsigned short p[4];
        #pragma unroll
        for (int r=0;r<4;++r){
          float va = fmaxf(fmaf(y[r][k], sca[k], sha[k]), 0.f);
          cs[k] += va;
          p[r] = f2bu(va);
        }
        uint2 pk; pk.x = p[0] | ((unsigned)p[1]<<16); pk.y = p[2] | ((unsigned)p[3]<<16);
        *(uint2*)&H3T[(cg*4+k)*68 + rg*4] = pk;
      }
    }
    __syncthreads();
    #pragma unroll
    for (int kc=0;kc<64;kc+=16){
      Frag a, b0, b1;
      const short* ap  = &H3T[arow  + kc + ko];
      const short* bp0 = &H3T[brow0 + kc + ko];
      const short* bp1 = &H3T[brow1 + kc + ko];
      a.u2[0]  = *(const uint2*)ap;   a.u2[1]  = *(const uint2*)(ap+4);
      b0.u2[0] = *(const uint2*)bp0;  b0.u2[1] = *(const uint2*)(bp0+4);
      b1.u2[0] = *(const uint2*)bp1;  b1.u2[1] = *(const uint2*)(bp1+4);
      acc0 = __builtin_amdgcn_mfma_f32_32x32x16_bf16(a.v, b0.v, acc0, 0, 0, 0);
      acc1 = __builtin_amdgcn_mfma_f32_32x32x16_bf16(a.v, b1.v, acc1, 0, 0, 0);
    }
    __syncthreads();
  }
  int col = lane & 31, rbase = 4*(lane>>5);
  #pragma unroll
  for (int r=0;r<16;++r){
    int row = (r&3) + 8*(r>>2) + rbase;
    atomicAdd(&G4[(size_t)(mt*32+row)*128 + nt0*32+col], acc0[r]);
    atomicAdd(&G4[(size_t)(mt*32+row)*128 + nt1*32+col], acc1[r]);
  }
  #pragma unroll
  for (int k=0;k<4;++k) atomicAdd(&sum4[cg*4+k], cs[k]);
}

// ---------------- fused layers 3+4 v3: VALU-bound blocking ----------------
__global__ __launch_bounds__(512,2) void fl34_kernel(const bf16* __restrict__ H2,
    const float* __restrict__ W3f, const float* __restrict__ sc3v, const float* __restrict__ sh3v,
    const float* __restrict__ W4f, const float* __restrict__ sc4v, const float* __restrict__ sh4v,
    bf16* __restrict__ cat){
  __shared__ float h2s[4][Kk][64];      // 20 KB
  __shared__ float h3s[4][Kk][128];     // 40 KB
  __shared__ float w4s[16*256];         // 16 KB; swizzled W4 rows; aliased as mm3/mmf
  int tid = threadIdx.x;
  int bn0 = blockIdx.x*4;
  int pt = tid >> 7, tid2 = tid & 127;
  for (int u=tid; u<4*Kk*64; u+=512){
    int p = u / 1280, rem = u - p*1280;
    h2s[p][rem>>6][rem&63] = b2f(H2[((size_t)(bn0+p)*Kk + (rem>>6))*64 + (rem&63)]);
  }
  __syncthreads();
  // stage 1: 5 rows x 4 cols per thread; W3 from global (L1-resident); i-ascending chains
  {
    int rg = tid2 >> 5, cgq = tid2 & 31, c0 = cgq*4;
    float acc[5][4];
    #pragma unroll
    for (int l=0;l<5;++l)
      #pragma unroll
      for (int k=0;k<4;++k) acc[l][k]=0.f;
    for (int i0=0;i0<64;i0+=4){
      float4 h4[5];
      #pragma unroll
      for (int l=0;l<5;++l) h4[l] = *(const float4*)&h2s[pt][rg*5+l][i0];
      #pragma unroll
      for (int ii=0;ii<4;++ii){
        float4 wv = *(const float4*)&W3f[(size_t)(i0+ii)*128 + c0];
        #pragma unroll
        for (int l=0;l<5;++l){
          float hv = h4[l][ii];
          acc[l][0]=fmaf(hv,wv.x,acc[l][0]);
          acc[l][1]=fmaf(hv,wv.y,acc[l][1]);
          acc[l][2]=fmaf(hv,wv.z,acc[l][2]);
          acc[l][3]=fmaf(hv,wv.w,acc[l][3]);
        }
      }
    }
    float sca[4], sha[4];
    #pragma unroll
    for (int k=0;k<4;++k){ sca[k]=sc3v[c0+k]; sha[k]=sh3v[c0+k]; }
    float mx4[4] = {0.f,0.f,0.f,0.f};
    #pragma unroll
    for (int l=0;l<5;++l){
      float4 v4;
      float v0=fmaxf(fmaf(acc[l][0],sca[0],sha[0]),0.f);
      float v1=fmaxf(fmaf(acc[l][1],sca[1],sha[1]),0.f);
      float v2=fmaxf(fmaf(acc[l][2],sca[2],sha[2]),0.f);
      float v3=fmaxf(fmaf(acc[l][3],sca[3],sha[3]),0.f);
      mx4[0]=fmaxf(mx4[0],v0); mx4[1]=fmaxf(mx4[1],v1);
      mx4[2]=fmaxf(mx4[2],v2); mx4[3]=fmaxf(mx4[3],v3);
      v4 = make_float4(v0,v1,v2,v3);
      *(float4*)&h3s[pt][rg*5+l][c0] = v4;
    }
    float* mm3 = w4s;   // [4 pt][4 rg][128]
    #pragma unroll
    for (int k=0;k<4;++k) mm3[((pt*4+rg)<<7) + c0 + k] = mx4[k];
  }
  __syncthreads();
  // x3 maxpool over rowgroups
  {
    const float* mm3 = w4s;
    int p = tid >> 7, c = tid & 127;
    float M0 = fmaxf(fmaxf(mm3[((p*4+0)<<7)+c], mm3[((p*4+1)<<7)+c]),
                     fmaxf(mm3[((p*4+2)<<7)+c], mm3[((p*4+3)<<7)+c]));
    cat[(size_t)(bn0+p)*512 + 128 + c] = f2b(M0);
  }
  __syncthreads();
  // stage 2: 5 rows x 8 consecutive cols; h float4 along k; W4 swizzled b128 pairs
  int q = tid2 >> 5, cg = tid2 & 31, c0 = cg*8;
  int wg0 = sw6(2*cg)*4, wg1 = sw6(2*cg+1)*4;
  float acc[5][8];
  #pragma unroll
  for (int l=0;l<5;++l)
    #pragma unroll
    for (int cb=0;cb<8;++cb) acc[l][cb]=0.f;
  for (int i0=0;i0<128;i0+=16){
    for (int u=tid;u<4096;u+=512){
      int kk=u>>8, c=u&255;
      w4s[kk*256 + sw6(c>>2)*4 + (c&3)] = W4f[(size_t)(i0+kk)*256 + c];
    }
    __syncthreads();
    #pragma unroll
    for (int kk0=0;kk0<16;kk0+=4){
      float4 h4[5];
      #pragma unroll
      for (int l=0;l<5;++l) h4[l] = *(const float4*)&h3s[pt][q*5+l][i0+kk0];
      #pragma unroll
      for (int ii=0;ii<4;++ii){
        float4 wa = *(const float4*)&w4s[(kk0+ii)*256 + wg0];
        float4 wb = *(const float4*)&w4s[(kk0+ii)*256 + wg1];
        float wv[8] = {wa.x,wa.y,wa.z,wa.w,wb.x,wb.y,wb.z,wb.w};
        #pragma unroll
        for (int l=0;l<5;++l){
          float hv = h4[l][ii];
          #pragma unroll
          for (int cb=0;cb<8;++cb) acc[l][cb]=fmaf(hv,wv[cb],acc[l][cb]);
        }
      }
    }
    __syncthreads();
  }
  float sc[8],sh[8];
  #pragma unroll
  for (int cb=0;cb<8;++cb){ sc[cb]=sc4v[c0+cb]; sh[cb]=sh4v[c0+cb]; }
  float mx[8];
  #pragma unroll
  for (int cb=0;cb<8;++cb) mx[cb]=0.f;
  #pragma unroll
  for (int l=0;l<5;++l)
    #pragma unroll
    for (int cb=0;cb<8;++cb){
      float v=fmaxf(fmaf(acc[l][cb],sc[cb],sh[cb]),0.f);
      mx[cb]=fmaxf(mx[cb],v);
    }
  float* mmf = w4s;   // [4 pt][4 q][256]
  #pragma unroll
  for (int cb=0;cb<8;++cb) mmf[((pt*4+q)<<8) + c0 + cb] = mx[cb];
  __syncthreads();
  for (int u=tid; u<1024; u+=512){
    int p = u >> 8, c = u & 255;
    float M0 = fmaxf(fmaxf(mmf[((p*4+0)<<8)+c], mmf[((p*4+1)<<8)+c]),
                     fmaxf(mmf[((p*4+2)<<8)+c], mmf[((p*4+3)<<8)+c]));
    cat[(size_t)(bn0+p)*512 + 256 + c] = f2b(M0);
  }
}

// ---------------- layer 5: 16 rows/block ----------------
__global__ __launch_bounds__(256) void l5_kernel(const bf16* __restrict__ cat,
                                                const float* __restrict__ Wf,
                                                const float* __restrict__ scale,
                                                const float* __restrict__ shift,
                                                float* __restrict__ out){
  __shared__ float cr[16][512];
  __shared__ float ob[16][512];
  int tid = threadIdx.x;
  int bn0 = blockIdx.x*16;
  for (int v=tid; v<1024; v+=256){
    int row = v>>6, c0 = (v&63)*8;
    U4b u; u.q = *(const uint4*)&cat[(size_t)(bn0+row)*512 + c0];
    float f[8];
    #pragma unroll
    for (int j=0;j<8;++j) f[j] = bits2f(u.s[j]);
    *(float4*)&cr[row][c0]   = make_float4(f[0],f[1],f[2],f[3]);
    *(float4*)&cr[row][c0+4] = make_float4(f[4],f[5],f[6],f[7]);
  }
  __syncthreads();
  int rp = tid >> 6, cg = tid & 63, c0 = cg*8;
  int ra = rp*4;
  float acc[4][8];
  #pragma unroll
  for (int r=0;r<4;++r)
    #pragma unroll
    for (int cb=0;cb<8;++cb) acc[r][cb]=0.f;
  for (int i=0;i<512;++i){
    float h0 = cr[ra][i], h1 = cr[ra+1][i], h2v = cr[ra+2][i], h3 = cr[ra+3][i];
    const float* wp = Wf + (size_t)i*512 + c0;
    float4 wa = *(const float4*)wp;
    float4 wb = *(const float4*)(wp+4);
    float w[8] = {wa.x,wa.y,wa.z,wa.w,wb.x,wb.y,wb.z,wb.w};
    #pragma unroll
    for (int k=0;k<8;++k){
      acc[0][k] = fmaf(h0, w[k], acc[0][k]);
      acc[1][k] = fmaf(h1, w[k], acc[1][k]);
      acc[2][k] = fmaf(h2v, w[k], acc[2][k]);
      acc[3][k] = fmaf(h3, w[k], acc[3][k]);
    }
  }
  float sc[8], sh[8];
  #pragma unroll
  for (int k=0;k<8;++k){ sc[k]=scale[c0+k]; sh[k]=shift[c0+k]; }
  #pragma unroll
  for (int r=0;r<4;++r)
    #pragma unroll
    for (int k=0;k<8;++k)
      ob[ra+r][c0+k] = fmaxf(fmaf(acc[r][k], sc[k], sh[k]), 0.f);
  __syncthreads();
  int b = bn0 >> 12, n0 = bn0 & 4095;
  for (int u=tid; u<512; u+=256){
    float* op = out + ((size_t)b*512 + u)*4096 + n0;
    #pragma unroll
    for (int g=0; g<4; ++g){
      float4 v = make_float4(ob[g*4][u], ob[g*4+1][u], ob[g*4+2][u], ob[g*4+3][u]);
      *(float4*)(op + g*4) = v;
    }
  }
}

extern "C" void kernel_launch(void* const* d_in, const int* in_sizes, int n_in,
                              void* d_out, int out_size, void* d_ws, size_t ws_size,
                              hipStream_t stream){
  const float* x   = (const float*)d_in[0];
  const float* W1f = (const float*)d_in[1];
  const float* W2f = (const float*)d_in[2];
  const float* W3f = (const float*)d_in[3];
  const float* W4f = (const float*)d_in[4];
  const float* W5f = (const float*)d_in[5];
  const float* g1=(const float*)d_in[6],  *b1=(const float*)d_in[7];
  const float* g2=(const float*)d_in[8],  *b2=(const float*)d_in[9];
  const float* g3=(const float*)d_in[10], *b3=(const float*)d_in[11];
  const float* g4=(const float*)d_in[12], *b4=(const float*)d_in[13];
  const float* g5=(const float*)d_in[14], *b5=(const float*)d_in[15];
  float* out = (float*)d_out;

  char* w = (char*)d_ws;
  size_t off = 0;
  auto alloc = [&](size_t bytes)->void*{
    void* p = w + off;
    off = (off + bytes + 255) & ~(size_t)255;
    return p;
  };

  int*  idxb = (int*) alloc((size_t)BN*Kk*4);
  bf16* H2   = (bf16*)alloc((size_t)Mrows*64*2);
  bf16* catb = (bf16*)alloc((size_t)BN*512*2);
  float* pv  = (float*)H2;
  int*   pib = (int*)((char*)H2 + (size_t)BN*4*Kk*4);

  size_t statsStart = off;
  float* partf=(float*)alloc(256*48*4);
  float* Gf=(float*)alloc(36*4);
  float* sumf=(float*)alloc(8*4);
  float* G2=(float*)alloc(4096*4);   float* sum2=(float*)alloc(64*4);
  float* G3=(float*)alloc(4096*4);   float* sum3=(float*)alloc(64*4);
  float* G4=(float*)alloc(16384*4);  float* sum4=(float*)alloc(128*4);
  float* G5=(float*)alloc(262144*4); float* sum5=(float*)alloc(512*4);
  float* P1=(float*)alloc(384*4);
  float* P2=(float*)alloc(4096*4);
  float* P3=(float*)alloc(8192*4);
  float* P4=(float*)alloc(32768*4);
  float* P5=(float*)alloc(262144*4);
  float* sc1=(float*)alloc(64*4);   float* sh1=(float*)alloc(64*4);
  float* sc2=(float*)alloc(64*4);   float* sh2=(float*)alloc(64*4);
  float* sc3=(float*)alloc(128*4);  float* sh3=(float*)alloc(128*4);
  float* sc4=(float*)alloc(256*4);  float* sh4=(float*)alloc(256*4);
  float* sc5=(float*)alloc(512*4);  float* sh5=(float*)alloc(512*4);
  size_t statsEnd = off;

  int statsFloats = (int)((statsEnd - statsStart)/4);
  zero_kernel<<<(statsFloats+255)/256,256,0,stream>>>((float*)(w+statsStart), statsFloats);

  knnA_kernel<<<512,256,0,stream>>>(x, pv, pib);
  knnB_kernel<<<BN/256,256,0,stream>>>(pv, pib, idxb);

  const float invM  = 1.0f/(float)Mrows;
  const float invM5 = 1.0f/(float)BN;

  gramf_kernel<<<256,256,0,stream>>>(x, idxb, partf);
  reducef_kernel<<<1,64,0,stream>>>(partf, Gf, sumf);
  kP_kernel<<<2,256,0,stream>>>(Gf, W1f, P1, 6, 64);
  kFinal_kernel<<<1,256,0,stream>>>(P1, sumf, W1f, g1, b1, sc1, sh1, 6, 64, invM);

  stats2_kernel<<<512,512,0,stream>>>(x, idxb, W1f, sc1, sh1, G2, sum2);
  kP_kernel<<<16,256,0,stream>>>(G2, W2f, P2, 64, 64);
  kFinal_kernel<<<1,256,0,stream>>>(P2, sum2, W2f, g2, b2, sc2, sh2, 64, 64, invM);

  fl12_kernel<<<BN,64,0,stream>>>(x, idxb, W1f, sc1, sh1, W2f, sc2, sh2, H2, catb);

  colsum_kernel<64,bf16><<<512,256,0,stream>>>(H2, Mrows, sum3);
  gramM_kernel<64><<<512,256,0,stream>>>(H2, Mrows, G3);
  kP_kernel<<<32,256,0,stream>>>(G3, W3f, P3, 64, 128);
  kFinal_kernel<<<1,256,0,stream>>>(P3, sum3, W3f, g3, b3, sc3, sh3, 64, 128, invM);

  stats4_kernel<<<512,512,0,stream>>>(H2, W3f, sc3, sh3, G4, sum4);
  kP_kernel<<<128,256,0,stream>>>(G4, W4f, P4, 128, 256);
  kFinal_kernel<<<1,256,0,stream>>>(P4, sum4, W4f, g4, b4, sc4, sh4, 128, 256, invM);

  fl34_kernel<<<BN/4,512,0,stream>>>(H2, W3f, sc3, sh3, W4f, sc4, sh4, catb);

  colsum_kernel<512,bf16><<<512,256,0,stream>>>(catb, BN, sum5);
  gramM_kernel<512><<<512,256,0,stream>>>(catb, BN, G5);
  kP_kernel<<<1024,256,0,stream>>>(G5, W5f, P5, 512, 512);
  kFinal_kernel<<<2,256,0,stream>>>(P5, sum5, W5f, g5, b5, sc5, sh5, 512, 512, invM5);
  l5_kernel<<<BN/16,256,0,stream>>>(catb, W5f, sc5, sh5, out);
}